// Round 12
// baseline (1078.795 us; speedup 1.0000x reference)
//
#include <hip/hip_runtime.h>
#include <cstdint>
#include <cstddef>

typedef _Float16 half8 __attribute__((ext_vector_type(8)));
typedef _Float16 half4 __attribute__((ext_vector_type(4)));
typedef float    floatx4 __attribute__((ext_vector_type(4)));

constexpr int N_ROWS = 32768;
constexpr int D_DIM  = 1024;
constexpr int K_CENT = 4096;
constexpr int CAP    = 4096;      // max uncertain rows (E[count]~620)
constexpr int KSL    = 4;         // pass1 K split (1024 cols/slice)
constexpr int RSL    = 8;         // rescore K split (512 cols/slice)
constexpr float EPS_GAP = 0.4f;   // 2 * (14-sigma hh-error bound)

__device__ __forceinline__ void gload_lds16(const void* g, void* l) {
    __builtin_amdgcn_global_load_lds(
        (const __attribute__((address_space(1))) uint32_t*)g,
        (__attribute__((address_space(3))) uint32_t*)l, 16, 0, 0);
}

// ============================================================================
// Pre-pass 1: C[d][k] f32 -> C_hiT[k][d], C_loT[k][d] fp16 (transposed split)
// ============================================================================
__global__ __launch_bounds__(256) void convert_C_kernel(
    const float* __restrict__ C, _Float16* __restrict__ ChiT, _Float16* __restrict__ CloT)
{
    __shared__ float tile[32][33];
    const int bk = blockIdx.x, bd = blockIdx.y, t = threadIdx.x;
    const int r = t >> 3, c4 = (t & 7) * 4;
    const float4 v = *(const float4*)&C[(size_t)(bd * 32 + r) * K_CENT + bk * 32 + c4];
    tile[r][c4 + 0] = v.x; tile[r][c4 + 1] = v.y;
    tile[r][c4 + 2] = v.z; tile[r][c4 + 3] = v.w;
    __syncthreads();
    half4 h, l;
#pragma unroll
    for (int i = 0; i < 4; ++i) {
        const float f = tile[c4 + i][r];
        const _Float16 hi = (_Float16)f;
        h[i] = hi;
        l[i] = (_Float16)(f - (float)hi);
    }
    *(half4*)&ChiT[(size_t)(bk * 32 + r) * D_DIM + bd * 32 + c4] = h;
    *(half4*)&CloT[(size_t)(bk * 32 + r) * D_DIM + bd * 32 + c4] = l;
}

// ============================================================================
// Pre-pass 2: x f32 -> x_hi fp16 (elementwise)
// ============================================================================
__global__ __launch_bounds__(256) void convert_x_kernel(
    const float* __restrict__ x, _Float16* __restrict__ xh)
{
    const size_t g = (size_t)blockIdx.x * 256 + threadIdx.x;   // 8 elems each
    const float4 v0 = *(const float4*)&x[g * 8];
    const float4 v1 = *(const float4*)&x[g * 8 + 4];
    half8 h;
    h[0] = (_Float16)v0.x; h[1] = (_Float16)v0.y; h[2] = (_Float16)v0.z; h[3] = (_Float16)v0.w;
    h[4] = (_Float16)v1.x; h[5] = (_Float16)v1.y; h[6] = (_Float16)v1.z; h[7] = (_Float16)v1.w;
    *(half8*)&xh[g * 8] = h;
}

// ============================================================================
// Pass 1 (flatmm style): hh-only GEMM, 128x128 block tile, 256 thr / 4 waves
// (2x2), per-wave 64x64 (acc[4][4]).  NO LDS, NO barriers in the main loop:
// each wave loads its MFMA fragments DIRECTLY from global (L1/L2-shared),
// 8 x global_load_dwordx4 + 16 MFMA per BK=32 step.  Latency hidden by TLP:
// __launch_bounds__(256,4) -> 128 regs/wave -> 16 waves/CU; grid 1024 = 4
// blocks/CU in one round.  Fragment identity (derived from the verified LDS
// path): frag(l15,l4) of subtile s = src[(s*16 + l15)*D + kd + l4*8 .. +7].
// KSL=4, XCD-bijective: each XCD owns one 2MB C-slice in its L2.
// ============================================================================
__global__ __launch_bounds__(256, 4) void kmeans_pass1(
    const _Float16* __restrict__ xh, const _Float16* __restrict__ ChiT,
    const float* __restrict__ Cnorm,
    float* __restrict__ m1buf, int* __restrict__ i1buf, float* __restrict__ m2buf)
{
    __shared__ float red_d[2][64][2];
    __shared__ int   red_i[2][64][2];
    __shared__ float red_2[2][64][2];

    // bijective: xcd = bid&7; ks = xcd&3; rb = (bid>>3)*2 + (xcd>>2)  (1024 blocks)
    const int bid  = blockIdx.x;
    const int xcd  = bid & 7;
    const int ks   = xcd & 3;
    const int rb   = (bid >> 3) * 2 + (xcd >> 2);   // 0..255
    const int row0 = rb * 128;
    const int kb0  = ks * (K_CENT / KSL);

    const int tid  = threadIdx.x;
    const int lane = tid & 63;
    const int wid  = tid >> 6;          // 0..3
    const int wm   = wid >> 1;          // 0..1 (64-row half)
    const int wn   = wid & 1;           // 0..1 (64-col half)

    const int l15 = lane & 15;
    const int l4  = lane >> 4;

    // per-lane fragment base pointers (A: x rows; B: C cols)
    const _Float16* paB = xh   + (size_t)(row0 + wm * 64 + l15) * D_DIM + l4 * 8;
    const _Float16* pbB = ChiT + (size_t)(kb0  + wn * 64 + l15) * D_DIM + l4 * 8;

    float rm1 = 3.4e38f, rm2 = 3.4e38f;
    int   ri1 = 0;

    constexpr int NCH = (K_CENT / KSL) / 128;   // 8 chunks of 128 cols

    for (int ci = 0; ci < NCH; ++ci) {
        const _Float16* pb = pbB + (size_t)ci * 128 * D_DIM;

        floatx4 acc[4][4];
#pragma unroll
        for (int i = 0; i < 4; ++i)
#pragma unroll
            for (int j = 0; j < 4; ++j) acc[i][j] = (floatx4)0.0f;

#pragma unroll 4
        for (int kdi = 0; kdi < 32; ++kdi) {
            const int kd = kdi * 32;
            half8 ah[4], bh[4];
#pragma unroll
            for (int i = 0; i < 4; ++i)
                ah[i] = *(const half8*)(paB + (size_t)i * 16 * D_DIM + kd);
#pragma unroll
            for (int j = 0; j < 4; ++j)
                bh[j] = *(const half8*)(pb + (size_t)j * 16 * D_DIM + kd);

            __builtin_amdgcn_s_setprio(1);
#pragma unroll
            for (int i = 0; i < 4; ++i)
#pragma unroll
                for (int j = 0; j < 4; ++j)
                    acc[i][j] = __builtin_amdgcn_mfma_f32_16x16x32_f16(ah[i], bh[j], acc[i][j], 0, 0, 0);
            __builtin_amdgcn_s_setprio(0);
        }

        // ---- per-chunk argmin epilogue (chunk = 128 cols)
        const int colw = ci * 128 + wn * 64;
        float cn4[4];
#pragma unroll
        for (int j = 0; j < 4; ++j) cn4[j] = Cnorm[kb0 + colw + j * 16 + l15];

#pragma unroll
        for (int i = 0; i < 4; ++i)
#pragma unroll
            for (int r = 0; r < 4; ++r) {
                float m1 = 3.4e38f, m2 = 3.4e38f;
                int   i1 = 0;
#pragma unroll
                for (int j = 0; j < 4; ++j) {
                    const float d  = fmaf(-2.0f, acc[i][j][r], cn4[j]);
                    const int   ix = kb0 + colw + j * 16 + l15;
                    if (d < m1) { m2 = m1; m1 = d; i1 = ix; }
                    else if (d < m2) { m2 = d; }
                }
#pragma unroll
                for (int off = 1; off < 16; off <<= 1) {
                    const float om1 = __shfl_xor(m1, off, 64);
                    const int   oi  = __shfl_xor(i1, off, 64);
                    const float om2 = __shfl_xor(m2, off, 64);
                    const float nm2 = fminf(fminf(m2, om2), fmaxf(m1, om1));
                    if (om1 < m1 || (om1 == m1 && oi < i1)) { m1 = om1; i1 = oi; }
                    m2 = nm2;
                }
                if (l15 == 0) {
                    const int rr = i * 16 + l4 * 4 + r;
                    red_d[wm][rr][wn] = m1;
                    red_i[wm][rr][wn] = i1;
                    red_2[wm][rr][wn] = m2;
                }
            }
        __syncthreads();

        if (tid < 128) {
            const int h2 = tid >> 6;
            const int r2 = tid & 63;
            float m1 = red_d[h2][r2][0], m2 = red_2[h2][r2][0];
            int   i1 = red_i[h2][r2][0];
            const float om1 = red_d[h2][r2][1];
            const int   oi  = red_i[h2][r2][1];
            const float om2 = red_2[h2][r2][1];
            m2 = fminf(fminf(m2, om2), fmaxf(m1, om1));
            if (om1 < m1 || (om1 == m1 && oi < i1)) { m1 = om1; i1 = oi; }
            const float nm2 = fminf(fminf(rm2, m2), fmaxf(rm1, m1));
            if (m1 < rm1 || (m1 == rm1 && i1 < ri1)) { rm1 = m1; ri1 = i1; }
            rm2 = nm2;
        }
        __syncthreads();   // red arrays free for next chunk
    }

    if (tid < 128) {
        const size_t off = (size_t)ks * N_ROWS + row0 + tid;
        m1buf[off] = rm1;
        i1buf[off] = ri1;
        m2buf[off] = rm2;
    }
}

// ============================================================================
// Merge K-slices: final argmin + certainty test + worklist
// ============================================================================
__global__ __launch_bounds__(256) void kmeans_merge4(
    const float* __restrict__ m1buf, const int* __restrict__ i1buf,
    const float* __restrict__ m2buf, int* __restrict__ out,
    int* __restrict__ urows, unsigned int* __restrict__ ucount)
{
    const int row = blockIdx.x * 256 + threadIdx.x;
    float m1 = m1buf[row], m2 = m2buf[row];
    int   i1 = i1buf[row];
#pragma unroll
    for (int s = 1; s < KSL; ++s) {
        const float om1 = m1buf[(size_t)s * N_ROWS + row];
        const float om2 = m2buf[(size_t)s * N_ROWS + row];
        const int   oi  = i1buf[(size_t)s * N_ROWS + row];
        const float nm2 = fminf(fminf(m2, om2), fmaxf(m1, om1));
        if (om1 < m1 || (om1 == m1 && oi < i1)) { m1 = om1; i1 = oi; }
        m2 = nm2;
    }
    out[row] = i1;
    if (m2 - m1 <= EPS_GAP) {
        const unsigned slot = atomicAdd(ucount, 1u);
        if (slot < (unsigned)CAP) urows[slot] = row;
    }
}

// ============================================================================
// Gather: uncertain rows' x -> compact fp16 hi/lo buffers [slot][1024]
// ============================================================================
__global__ __launch_bounds__(64) void kmeans_gather(
    const float* __restrict__ x, const int* __restrict__ urows,
    const unsigned int* __restrict__ ucount,
    _Float16* __restrict__ xch, _Float16* __restrict__ xcl)
{
    const unsigned cntr = *ucount;
    const unsigned cnt = cntr > (unsigned)CAP ? (unsigned)CAP : cntr;
    const unsigned slot = blockIdx.x;
    if (slot >= cnt) return;
    const int row = urows[slot];
    const int t = threadIdx.x;
#pragma unroll
    for (int e = 0; e < 16; ++e) {
        const int idx = e * 64 + t;
        const float v = x[(size_t)row * D_DIM + idx];
        const _Float16 h = (_Float16)v;
        xch[(size_t)slot * D_DIM + idx] = h;
        xcl[(size_t)slot * D_DIM + idx] = (_Float16)(v - (float)h);
    }
}

// ============================================================================
// Rescore (K-split x8): exact 3-pass hi/lo over 512-col slice for 32 rows.
// ============================================================================
constexpr int R_XH = 0;        // 1024 halves (2 sub)
constexpr int R_XL = 1024;     // 1024
constexpr int R_CH = 2048;     // 8192 (16 sub)
constexpr int R_CL = 10240;    // 8192
constexpr int R_HB = 18432;    // per buffer (36 KB)

__global__ __launch_bounds__(256) void kmeans_rescore2(
    const _Float16* __restrict__ xch, const _Float16* __restrict__ xcl,
    const _Float16* __restrict__ ChiT, const _Float16* __restrict__ CloT,
    const float* __restrict__ Cnorm, const unsigned int* __restrict__ ucount,
    float* __restrict__ rpd, int* __restrict__ rpi)
{
    const unsigned cntr = *ucount;
    const unsigned cnt = cntr > (unsigned)CAP ? (unsigned)CAP : cntr;
    const int bid = blockIdx.x;
    const int ksl = bid & 7;
    const int grp = bid >> 3;
    if ((unsigned)(grp * 32) >= cnt) return;

    __shared__ _Float16 lds[2][R_HB];
    __shared__ float rd[32][4];
    __shared__ int   ri[32][4];

    const int tid  = threadIdx.x;
    const int lane = tid & 63;
    const int wid  = tid >> 6;
    const int l15  = lane & 15;
    const int l4   = lane >> 4;
    const int kge  = l4 ^ ((l15 >> 1) & 3);
    const int fragoff = l15 * 32 + kge * 8;
    const int scol = lane >> 2;
    const int skg  = (lane & 3) ^ ((scol >> 1) & 3);

    const int base  = grp * 32;
    const int kbase = ksl * (K_CENT / RSL);

    float best[2][4];
    int   bidx[2][4];
#pragma unroll
    for (int i = 0; i < 2; ++i)
#pragma unroll
        for (int r = 0; r < 4; ++r) { best[i][r] = 3.4e38f; bidx[i][r] = 0; }

    for (int ch = 0; ch < 2; ++ch) {
        const int kc = kbase + ch * 256;
        floatx4 acc[2][4];
#pragma unroll
        for (int i = 0; i < 2; ++i)
#pragma unroll
            for (int j = 0; j < 4; ++j) acc[i][j] = (floatx4)0.0f;

        {
            _Float16* buf = lds[0];
#pragma unroll
            for (int q = 0; q < 4; ++q) {
                const int sub = wid * 4 + q;
                gload_lds16(&ChiT[(size_t)(kc + sub * 16 + scol) * D_DIM + 0 + skg * 8], buf + R_CH + sub * 512);
                gload_lds16(&CloT[(size_t)(kc + sub * 16 + scol) * D_DIM + 0 + skg * 8], buf + R_CL + sub * 512);
            }
            if (wid < 2)
                gload_lds16(&xch[(size_t)(base + wid * 16 + scol) * D_DIM + 0 + skg * 8], buf + R_XH + wid * 512);
            else
                gload_lds16(&xcl[(size_t)(base + (wid - 2) * 16 + scol) * D_DIM + 0 + skg * 8], buf + R_XL + (wid - 2) * 512);
            __syncthreads();
        }

        for (int kdi = 0; kdi < D_DIM / 32; ++kdi) {
            const int cur = kdi & 1;
            _Float16* bufc = lds[cur];
            _Float16* bufn = lds[cur ^ 1];
            const int  kdn = (kdi + 1) * 32;
            const bool pf  = (kdi + 1 < D_DIM / 32);

            if (pf) {
#pragma unroll
                for (int q = 0; q < 4; ++q) {
                    const int sub = wid * 4 + q;
                    gload_lds16(&ChiT[(size_t)(kc + sub * 16 + scol) * D_DIM + kdn + skg * 8], bufn + R_CH + sub * 512);
                    gload_lds16(&CloT[(size_t)(kc + sub * 16 + scol) * D_DIM + kdn + skg * 8], bufn + R_CL + sub * 512);
                }
                if (wid < 2)
                    gload_lds16(&xch[(size_t)(base + wid * 16 + scol) * D_DIM + kdn + skg * 8], bufn + R_XH + wid * 512);
                else
                    gload_lds16(&xcl[(size_t)(base + (wid - 2) * 16 + scol) * D_DIM + kdn + skg * 8], bufn + R_XL + (wid - 2) * 512);
            }

            half8 ah[2], al[2], bh[4], bl[4];
#pragma unroll
            for (int i = 0; i < 2; ++i) {
                ah[i] = *(const half8*)(bufc + R_XH + i * 512 + fragoff);
                al[i] = *(const half8*)(bufc + R_XL + i * 512 + fragoff);
            }
#pragma unroll
            for (int j = 0; j < 4; ++j) {
                bh[j] = *(const half8*)(bufc + R_CH + (wid * 4 + j) * 512 + fragoff);
                bl[j] = *(const half8*)(bufc + R_CL + (wid * 4 + j) * 512 + fragoff);
            }
#pragma unroll
            for (int i = 0; i < 2; ++i)
#pragma unroll
                for (int j = 0; j < 4; ++j) {
                    acc[i][j] = __builtin_amdgcn_mfma_f32_16x16x32_f16(ah[i], bh[j], acc[i][j], 0, 0, 0);
                    acc[i][j] = __builtin_amdgcn_mfma_f32_16x16x32_f16(ah[i], bl[j], acc[i][j], 0, 0, 0);
                    acc[i][j] = __builtin_amdgcn_mfma_f32_16x16x32_f16(al[i], bh[j], acc[i][j], 0, 0, 0);
                }
            __syncthreads();
        }

#pragma unroll
        for (int j = 0; j < 4; ++j) {
            const int col = kc + wid * 64 + j * 16 + l15;
            const float cn = Cnorm[col];
#pragma unroll
            for (int i = 0; i < 2; ++i)
#pragma unroll
                for (int r = 0; r < 4; ++r) {
                    const float d = fmaf(-2.0f, acc[i][j][r], cn);
                    if (d < best[i][r]) { best[i][r] = d; bidx[i][r] = col; }
                }
        }
    }

#pragma unroll
    for (int i = 0; i < 2; ++i)
#pragma unroll
        for (int r = 0; r < 4; ++r) {
            float m1 = best[i][r];
            int   i1 = bidx[i][r];
#pragma unroll
            for (int off = 1; off < 16; off <<= 1) {
                const float om1 = __shfl_xor(m1, off, 64);
                const int   oi  = __shfl_xor(i1, off, 64);
                if (om1 < m1 || (om1 == m1 && oi < i1)) { m1 = om1; i1 = oi; }
            }
            if (l15 == 0) { rd[i * 16 + l4 * 4 + r][wid] = m1; ri[i * 16 + l4 * 4 + r][wid] = i1; }
        }
    __syncthreads();

    if (tid < 32) {
        float m1 = rd[tid][0];
        int   i1 = ri[tid][0];
#pragma unroll
        for (int w = 1; w < 4; ++w) {
            const float om1 = rd[tid][w];
            const int   oi  = ri[tid][w];
            if (om1 < m1 || (om1 == m1 && oi < i1)) { m1 = om1; i1 = oi; }
        }
        rpd[(size_t)(base + tid) * RSL + ksl] = m1;
        rpi[(size_t)(base + tid) * RSL + ksl] = i1;
    }
}

// ============================================================================
// Merge rescore slices -> final out for uncertain rows
// ============================================================================
__global__ __launch_bounds__(256) void kmeans_merge2(
    const float* __restrict__ rpd, const int* __restrict__ rpi,
    const int* __restrict__ urows, const unsigned int* __restrict__ ucount,
    int* __restrict__ out)
{
    const unsigned cntr = *ucount;
    const unsigned cnt = cntr > (unsigned)CAP ? (unsigned)CAP : cntr;
    const unsigned s = blockIdx.x * 256 + threadIdx.x;
    if (s >= cnt) return;
    float m1 = rpd[(size_t)s * RSL];
    int   i1 = rpi[(size_t)s * RSL];
#pragma unroll
    for (int k = 1; k < RSL; ++k) {
        const float om = rpd[(size_t)s * RSL + k];
        const int   oi = rpi[(size_t)s * RSL + k];
        if (om < m1 || (om == m1 && oi < i1)) { m1 = om; i1 = oi; }
    }
    out[urows[s]] = i1;
}

// ============================================================================
// Fallback A: proven R3 3-pass MFMA kernel (hi/lo, direct out)
// ============================================================================
constexpr int F_XH = 0, F_XL = 4096, F_CH = 8192, F_CL = 16384, F_HB = 24576;

__device__ __forceinline__ void write_x2(_Float16* buf, const float4 v, int r, int kb) {
    const _Float16 h0 = (_Float16)v.x, h1 = (_Float16)v.y;
    const _Float16 h2 = (_Float16)v.z, h3 = (_Float16)v.w;
    const int kg  = kb >> 3;
    const int hs  = (kb >> 2) & 1;
    const int kge = kg ^ ((r >> 1) & 3);
    const int base = (r >> 4) * 512 + (r & 15) * 32 + kge * 8 + hs * 4;
    *(half4*)(buf + F_XH + base) = (half4){h0, h1, h2, h3};
    *(half4*)(buf + F_XL + base) = (half4){(_Float16)(v.x - (float)h0), (_Float16)(v.y - (float)h1),
                                           (_Float16)(v.z - (float)h2), (_Float16)(v.w - (float)h3)};
}

__global__ __launch_bounds__(512, 2) void kmeans_mfma_kernel(
    const float* __restrict__ x, const _Float16* __restrict__ ChiT,
    const _Float16* __restrict__ CloT, const float* __restrict__ Cnorm,
    int* __restrict__ out)
{
    __shared__ _Float16 lds[2][F_HB];
    __shared__ float red_d[2][64][4];
    __shared__ int   red_i[2][64][4];

    const int tid  = threadIdx.x;
    const int lane = tid & 63;
    const int wid  = tid >> 6;
    const int wm   = wid >> 2;
    const int wn   = wid & 3;
    const int row0 = blockIdx.x * 128;
    const int l15 = lane & 15;
    const int l4  = lane >> 4;
    const int kge = l4 ^ ((l15 >> 1) & 3);
    const int fragoff = l15 * 32 + kge * 8;
    const int sr = tid >> 2, sc = tid & 3;
    const int ccol = lane >> 2;
    const int ckg  = (lane & 3) ^ ((ccol >> 1) & 3);

    float best[4][4];
    int   bidx[4][4];
#pragma unroll
    for (int i = 0; i < 4; ++i)
#pragma unroll
        for (int r = 0; r < 4; ++r) { best[i][r] = 3.4e38f; bidx[i][r] = 0; }

    for (int kc = 0; kc < K_CENT; kc += 256) {
        floatx4 acc[4][4];
#pragma unroll
        for (int i = 0; i < 4; ++i)
#pragma unroll
            for (int j = 0; j < 4; ++j) acc[i][j] = (floatx4)0.0f;
        {
            _Float16* buf = lds[0];
            const float4 xv0 = *(const float4*)&x[(size_t)(row0 + sr) * D_DIM + 0 + sc * 4];
            const float4 xv1 = *(const float4*)&x[(size_t)(row0 + sr) * D_DIM + 16 + sc * 4];
            gload_lds16(&ChiT[(size_t)(kc + wid * 16 + ccol) * D_DIM + 0 + ckg * 8], buf + F_CH + wid * 512);
            gload_lds16(&ChiT[(size_t)(kc + (wid + 8) * 16 + ccol) * D_DIM + 0 + ckg * 8], buf + F_CH + (wid + 8) * 512);
            gload_lds16(&CloT[(size_t)(kc + wid * 16 + ccol) * D_DIM + 0 + ckg * 8], buf + F_CL + wid * 512);
            gload_lds16(&CloT[(size_t)(kc + (wid + 8) * 16 + ccol) * D_DIM + 0 + ckg * 8], buf + F_CL + (wid + 8) * 512);
            write_x2(buf, xv0, sr, sc * 4);
            write_x2(buf, xv1, sr, sc * 4 + 16);
            __syncthreads();
        }
        for (int kdi = 0; kdi < D_DIM / 32; ++kdi) {
            const int cur = kdi & 1;
            _Float16* bufc = lds[cur];
            _Float16* bufn = lds[cur ^ 1];
            const int  kdn = (kdi + 1) * 32;
            const bool pf  = (kdi + 1 < D_DIM / 32);
            float4 xv0, xv1;
            if (pf) {
                xv0 = *(const float4*)&x[(size_t)(row0 + sr) * D_DIM + kdn + sc * 4];
                xv1 = *(const float4*)&x[(size_t)(row0 + sr) * D_DIM + kdn + 16 + sc * 4];
                gload_lds16(&ChiT[(size_t)(kc + wid * 16 + ccol) * D_DIM + kdn + ckg * 8], bufn + F_CH + wid * 512);
                gload_lds16(&ChiT[(size_t)(kc + (wid + 8) * 16 + ccol) * D_DIM + kdn + ckg * 8], bufn + F_CH + (wid + 8) * 512);
                gload_lds16(&CloT[(size_t)(kc + wid * 16 + ccol) * D_DIM + kdn + ckg * 8], bufn + F_CL + wid * 512);
                gload_lds16(&CloT[(size_t)(kc + (wid + 8) * 16 + ccol) * D_DIM + kdn + ckg * 8], bufn + F_CL + (wid + 8) * 512);
            }
            half8 ah[4], al[4], bh[4], bl[4];
#pragma unroll
            for (int i = 0; i < 4; ++i) {
                ah[i] = *(const half8*)(bufc + F_XH + (wm * 4 + i) * 512 + fragoff);
                al[i] = *(const half8*)(bufc + F_XL + (wm * 4 + i) * 512 + fragoff);
            }
#pragma unroll
            for (int j = 0; j < 4; ++j) {
                bh[j] = *(const half8*)(bufc + F_CH + (wn * 4 + j) * 512 + fragoff);
                bl[j] = *(const half8*)(bufc + F_CL + (wn * 4 + j) * 512 + fragoff);
            }
#pragma unroll
            for (int i = 0; i < 4; ++i)
#pragma unroll
                for (int j = 0; j < 4; ++j) {
                    acc[i][j] = __builtin_amdgcn_mfma_f32_16x16x32_f16(ah[i], bh[j], acc[i][j], 0, 0, 0);
                    acc[i][j] = __builtin_amdgcn_mfma_f32_16x16x32_f16(ah[i], bl[j], acc[i][j], 0, 0, 0);
                    acc[i][j] = __builtin_amdgcn_mfma_f32_16x16x32_f16(al[i], bh[j], acc[i][j], 0, 0, 0);
                }
            if (pf) {
                write_x2(bufn, xv0, sr, sc * 4);
                write_x2(bufn, xv1, sr, sc * 4 + 16);
            }
            __syncthreads();
        }
        const int colw = kc + wn * 64;
#pragma unroll
        for (int ns = 0; ns < 4; ++ns) {
            const float cn = Cnorm[colw + ns * 16 + l15];
            const int   ix = colw + ns * 16 + l15;
#pragma unroll
            for (int i = 0; i < 4; ++i)
#pragma unroll
                for (int r = 0; r < 4; ++r) {
                    const float d = fmaf(-2.0f, acc[i][ns][r], cn);
                    if (d < best[i][r]) { best[i][r] = d; bidx[i][r] = ix; }
                }
        }
    }
#pragma unroll
    for (int i = 0; i < 4; ++i)
#pragma unroll
        for (int r = 0; r < 4; ++r) {
            float d  = best[i][r];
            int   ix = bidx[i][r];
#pragma unroll
            for (int off = 1; off < 16; off <<= 1) {
                const float od = __shfl_xor(d, off, 64);
                const int   oi = __shfl_xor(ix, off, 64);
                if (od < d || (od == d && oi < ix)) { d = od; ix = oi; }
            }
            if (l15 == 0) {
                red_d[wm][i * 16 + l4 * 4 + r][wn] = d;
                red_i[wm][i * 16 + l4 * 4 + r][wn] = ix;
            }
        }
    __syncthreads();
    if (tid < 128) {
        const int hh = tid >> 6, rr = tid & 63;
        float bd = red_d[hh][rr][0];
        int   bi2 = red_i[hh][rr][0];
#pragma unroll
        for (int w = 1; w < 4; ++w) {
            const float od = red_d[hh][rr][w];
            const int   oi = red_i[hh][rr][w];
            if (od < bd || (od == bd && oi < bi2)) { bd = od; bi2 = oi; }
        }
        out[row0 + tid] = bi2;
    }
}

// ============================================================================
// Fallback B: R1 fp32 kernel
// ============================================================================
__global__ __launch_bounds__(256, 2) void kmeans_assign_f32(
    const float* __restrict__ x, const float* __restrict__ Cm,
    const float* __restrict__ Cnorm, int* __restrict__ out)
{
    __shared__ float xs[32][64];
    __shared__ float cs[32][64];
    const int tid = threadIdx.x;
    const int tx = tid & 15, ty = tid >> 4;
    const int row0 = blockIdx.x * 64;
    const int xr = tid >> 3, xc = tid & 7;
    const int cr = tid >> 4, cc = tid & 15;
    float best[4]; int bidx[4];
#pragma unroll
    for (int i = 0; i < 4; ++i) { best[i] = 3.4e38f; bidx[i] = 0; }
    for (int kc = 0; kc < K_CENT; kc += 64) {
        float acc[16];
#pragma unroll
        for (int i = 0; i < 16; ++i) acc[i] = 0.0f;
        for (int kd = 0; kd < D_DIM; kd += 32) {
            const float4 xv0 = *(const float4*)&x[(size_t)(row0 + xr) * D_DIM + kd + xc * 4];
            const float4 xv1 = *(const float4*)&x[(size_t)(row0 + xr + 32) * D_DIM + kd + xc * 4];
            const float4 cv0 = *(const float4*)&Cm[(size_t)(kd + cr) * K_CENT + kc + cc * 4];
            const float4 cv1 = *(const float4*)&Cm[(size_t)(kd + cr + 16) * K_CENT + kc + cc * 4];
            __syncthreads();
            xs[xc*4+0][xr] = xv0.x; xs[xc*4+1][xr] = xv0.y; xs[xc*4+2][xr] = xv0.z; xs[xc*4+3][xr] = xv0.w;
            xs[xc*4+0][xr+32] = xv1.x; xs[xc*4+1][xr+32] = xv1.y; xs[xc*4+2][xr+32] = xv1.z; xs[xc*4+3][xr+32] = xv1.w;
            *(float4*)&cs[cr][cc*4]    = cv0;
            *(float4*)&cs[cr+16][cc*4] = cv1;
            __syncthreads();
#pragma unroll
            for (int kk = 0; kk < 32; ++kk) {
                const float4 a = *(const float4*)&xs[kk][ty*4];
                const float4 b = *(const float4*)&cs[kk][tx*4];
                acc[ 0] += a.x*b.x; acc[ 1] += a.x*b.y; acc[ 2] += a.x*b.z; acc[ 3] += a.x*b.w;
                acc[ 4] += a.y*b.x; acc[ 5] += a.y*b.y; acc[ 6] += a.y*b.z; acc[ 7] += a.y*b.w;
                acc[ 8] += a.z*b.x; acc[ 9] += a.z*b.y; acc[10] += a.z*b.z; acc[11] += a.z*b.w;
                acc[12] += a.w*b.x; acc[13] += a.w*b.y; acc[14] += a.w*b.z; acc[15] += a.w*b.w;
            }
        }
        const float4 cn = *(const float4*)&Cnorm[kc + tx*4];
        const float cnv[4] = {cn.x, cn.y, cn.z, cn.w};
#pragma unroll
        for (int i = 0; i < 4; ++i)
#pragma unroll
            for (int j = 0; j < 4; ++j) {
                const float dist = cnv[j] - 2.0f * acc[i*4+j];
                const int   idx  = kc + tx*4 + j;
                if (dist < best[i]) { best[i] = dist; bidx[i] = idx; }
            }
    }
#pragma unroll
    for (int i = 0; i < 4; ++i) {
        float d = best[i]; int ix = bidx[i];
#pragma unroll
        for (int off = 1; off < 16; off <<= 1) {
            const float od = __shfl_xor(d, off, 64);
            const int   oi = __shfl_xor(ix, off, 64);
            if (od < d || (od == d && oi < ix)) { d = od; ix = oi; }
        }
        if (tx == 0) out[row0 + ty*4 + i] = ix;
    }
}

// ============================================================================
extern "C" void kernel_launch(void* const* d_in, const int* in_sizes, int n_in,
                              void* d_out, int out_size, void* d_ws, size_t ws_size,
                              hipStream_t stream) {
    const float* x     = (const float*)d_in[0];
    const float* C     = (const float*)d_in[1];
    const float* Cnorm = (const float*)d_in[2];
    int* out = (int*)d_out;

    const size_t chalf = (size_t)K_CENT * D_DIM;   // halves per C array
    const size_t capd  = (size_t)CAP * D_DIM;      // halves per xc array
    const size_t xhN   = (size_t)N_ROWS * D_DIM;   // halves for x_hi

    const size_t sz_base = (2 * chalf + 2 * capd) * 2
                         + (size_t)KSL * N_ROWS * 12
                         + (size_t)CAP * RSL * 8
                         + (size_t)CAP * 4 + 64;
    const size_t need_full = sz_base + xhN * 2;
    const size_t need_r3   = 2 * chalf * 2;

    if (ws_size >= need_full) {
        _Float16* ChiT = (_Float16*)d_ws;
        _Float16* CloT = ChiT + chalf;
        _Float16* xch  = CloT + chalf;
        _Float16* xcl  = xch + capd;
        float* m1buf = (float*)(xcl + capd);
        float* m2buf = m1buf + (size_t)KSL * N_ROWS;
        int*   i1buf = (int*)(m2buf + (size_t)KSL * N_ROWS);
        float* rpd   = (float*)(i1buf + (size_t)KSL * N_ROWS);
        int*   rpi   = (int*)(rpd + (size_t)CAP * RSL);
        int*   urows = rpi + (size_t)CAP * RSL;
        unsigned int* ucount = (unsigned int*)(urows + CAP);
        _Float16* xh = (_Float16*)(ucount + 16);

        convert_C_kernel<<<dim3(128, 32), 256, 0, stream>>>(C, ChiT, CloT);
        convert_x_kernel<<<dim3((int)(xhN / 2048)), 256, 0, stream>>>(x, xh);
        hipMemsetAsync(ucount, 0, sizeof(unsigned int), stream);
        kmeans_pass1<<<dim3(256 * KSL), 256, 0, stream>>>(xh, ChiT, Cnorm, m1buf, i1buf, m2buf);
        kmeans_merge4<<<dim3(N_ROWS / 256), 256, 0, stream>>>(m1buf, i1buf, m2buf, out, urows, ucount);
        kmeans_gather<<<dim3(CAP), 64, 0, stream>>>(x, urows, ucount, xch, xcl);
        kmeans_rescore2<<<dim3((CAP / 32) * RSL), 256, 0, stream>>>(xch, xcl, ChiT, CloT, Cnorm, ucount, rpd, rpi);
        kmeans_merge2<<<dim3(CAP / 256), 256, 0, stream>>>(rpd, rpi, urows, ucount, out);
    } else if (ws_size >= need_r3) {
        _Float16* ChiT = (_Float16*)d_ws;
        _Float16* CloT = ChiT + chalf;
        convert_C_kernel<<<dim3(128, 32), 256, 0, stream>>>(C, ChiT, CloT);
        kmeans_mfma_kernel<<<dim3(N_ROWS / 128), 512, 0, stream>>>(x, ChiT, CloT, Cnorm, out);
    } else {
        kmeans_assign_f32<<<dim3(N_ROWS / 64), 256, 0, stream>>>(x, C, Cnorm, out);
    }
}

// Round 13
// 497.661 us; speedup vs baseline: 2.1677x; 2.1677x over previous
//
#include <hip/hip_runtime.h>
#include <cstdint>
#include <cstddef>

typedef _Float16 half8 __attribute__((ext_vector_type(8)));
typedef _Float16 half4 __attribute__((ext_vector_type(4)));
typedef float    floatx4 __attribute__((ext_vector_type(4)));

constexpr int N_ROWS = 32768;
constexpr int D_DIM  = 1024;
constexpr int K_CENT = 4096;
constexpr int CAP    = 4096;      // max uncertain rows (E[count]~620)
constexpr int KSL    = 4;         // pass1 K split (1024 cols/slice)
constexpr int RSL    = 8;         // rescore K split (512 cols/slice)
constexpr float EPS_GAP = 0.4f;   // 2 * (14-sigma hh-error bound)

__device__ __forceinline__ void gload_lds16(const void* g, void* l) {
    __builtin_amdgcn_global_load_lds(
        (const __attribute__((address_space(1))) uint32_t*)g,
        (__attribute__((address_space(3))) uint32_t*)l, 16, 0, 0);
}

// ============================================================================
// Pre-pass 1: C[d][k] f32 -> C_hiT[k][d], C_loT[k][d] fp16 (transposed split)
// ============================================================================
__global__ __launch_bounds__(256) void convert_C_kernel(
    const float* __restrict__ C, _Float16* __restrict__ ChiT, _Float16* __restrict__ CloT)
{
    __shared__ float tile[32][33];
    const int bk = blockIdx.x, bd = blockIdx.y, t = threadIdx.x;
    const int r = t >> 3, c4 = (t & 7) * 4;
    const float4 v = *(const float4*)&C[(size_t)(bd * 32 + r) * K_CENT + bk * 32 + c4];
    tile[r][c4 + 0] = v.x; tile[r][c4 + 1] = v.y;
    tile[r][c4 + 2] = v.z; tile[r][c4 + 3] = v.w;
    __syncthreads();
    half4 h, l;
#pragma unroll
    for (int i = 0; i < 4; ++i) {
        const float f = tile[c4 + i][r];
        const _Float16 hi = (_Float16)f;
        h[i] = hi;
        l[i] = (_Float16)(f - (float)hi);
    }
    *(half4*)&ChiT[(size_t)(bk * 32 + r) * D_DIM + bd * 32 + c4] = h;
    *(half4*)&CloT[(size_t)(bk * 32 + r) * D_DIM + bd * 32 + c4] = l;
}

// ============================================================================
// Pre-pass 2: x f32 -> x_hi fp16 (elementwise)
// ============================================================================
__global__ __launch_bounds__(256) void convert_x_kernel(
    const float* __restrict__ x, _Float16* __restrict__ xh)
{
    const size_t g = (size_t)blockIdx.x * 256 + threadIdx.x;   // 8 elems each
    const float4 v0 = *(const float4*)&x[g * 8];
    const float4 v1 = *(const float4*)&x[g * 8 + 4];
    half8 h;
    h[0] = (_Float16)v0.x; h[1] = (_Float16)v0.y; h[2] = (_Float16)v0.z; h[3] = (_Float16)v0.w;
    h[4] = (_Float16)v1.x; h[5] = (_Float16)v1.y; h[6] = (_Float16)v1.z; h[7] = (_Float16)v1.w;
    *(half8*)&xh[g * 8] = h;
}

// ============================================================================
// Pass 1 (m97 geometry + counted vmcnt + pointer-increment staging):
// hh-only GEMM, 128x128 block tile, 256 thr / 4 waves (2x2), per-wave 64x64
// (acc[4][4]), BK=32, 2-buffer dbuf.  Per step:
//   advance pa/pb (pure pointer adds) -> stage4(next) -> vmcnt(4) -> barrier
//   -> frag reads (compiler-scheduled lgkmcnt) -> 16 MFMA (setprio) -> barrier
// KSL=4 -> grid 1024 = 4 blocks/CU; __launch_bounds__(256,4) -> 16 waves/CU.
// XCD-bijective: each XCD owns one 2MB C-slice in its L2.
// ============================================================================
constexpr int Q_A  = 0;        // A subtiles: 8 x 512 halves (x_hi rows)
constexpr int Q_B  = 4096;     // B subtiles: 8 x 512 halves (C_hi cols)
constexpr int Q_HB = 8192;     // 16 KB per buffer

__global__ __launch_bounds__(256, 4) void kmeans_pass1(
    const _Float16* __restrict__ xh, const _Float16* __restrict__ ChiT,
    const float* __restrict__ Cnorm,
    float* __restrict__ m1buf, int* __restrict__ i1buf, float* __restrict__ m2buf)
{
    __shared__ _Float16 lds[2][Q_HB];      // 32 KB
    __shared__ float red_d[2][64][2];
    __shared__ int   red_i[2][64][2];
    __shared__ float red_2[2][64][2];

    // bijective: xcd = bid&7; ks = xcd&3; rb = (bid>>3)*2 + (xcd>>2)  (1024 blocks)
    const int bid  = blockIdx.x;
    const int xcd  = bid & 7;
    const int ks   = xcd & 3;
    const int rb   = (bid >> 3) * 2 + (xcd >> 2);   // 0..255
    const int row0 = rb * 128;
    const int kb0  = ks * (K_CENT / KSL);

    const int tid  = threadIdx.x;
    const int lane = tid & 63;
    const int wid  = tid >> 6;          // 0..3
    const int wm   = wid >> 1;          // 0..1 (64-row half)
    const int wn   = wid & 1;           // 0..1 (64-col half)

    const int l15 = lane & 15;
    const int l4  = lane >> 4;
    const int kge = l4 ^ ((l15 >> 1) & 3);
    const int fragoff = l15 * 32 + kge * 8;

    const int scol = lane >> 2;                       // 0..15
    const int skg  = (lane & 3) ^ ((scol >> 1) & 3);  // pre-swizzled source kg

    // staging pointers: point at the most recently staged (kd) position
    const _Float16* pa = xh   + (size_t)(row0 + (wid * 2) * 16 + scol) * D_DIM + skg * 8;
    const _Float16* pb = ChiT + (size_t)(kb0  + (wid * 2) * 16 + scol) * D_DIM + skg * 8;
    constexpr ptrdiff_t SIB = (ptrdiff_t)16 * D_DIM;  // sibling subtile (+16 rows)

    float rm1 = 3.4e38f, rm2 = 3.4e38f;
    int   ri1 = 0;

    constexpr int NCH = (K_CENT / KSL) / 128;   // 8 chunks of 128 cols

    // prologue: stage chunk0/kd0 into buf 0 (4 loads/wave in flight)
    gload_lds16(pa,       lds[0] + Q_A + (wid * 2 + 0) * 512);
    gload_lds16(pa + SIB, lds[0] + Q_A + (wid * 2 + 1) * 512);
    gload_lds16(pb,       lds[0] + Q_B + (wid * 2 + 0) * 512);
    gload_lds16(pb + SIB, lds[0] + Q_B + (wid * 2 + 1) * 512);

    floatx4 acc[4][4];
#pragma unroll
    for (int i = 0; i < 4; ++i)
#pragma unroll
        for (int j = 0; j < 4; ++j) acc[i][j] = (floatx4)0.0f;

    for (int ci = 0; ci < NCH; ++ci) {
        // hoist this chunk's Cnorm values (retire long before the epilogue)
        const int colw = ci * 128 + wn * 64;
        float cn4[4];
#pragma unroll
        for (int j = 0; j < 4; ++j) cn4[j] = Cnorm[kb0 + colw + j * 16 + l15];

#pragma unroll 2
        for (int kdi = 0; kdi < 32; ++kdi) {
            _Float16* bufc = lds[kdi & 1];
            _Float16* bufn = lds[(kdi + 1) & 1];
            const bool last = (kdi == 31) && (ci == NCH - 1);
            if (!last) {
                if (kdi < 31) { pa += 32;  pb += 32; }
                else          { pa -= 992; pb += 130080; }   // next chunk: kd->0, B rows +128
                gload_lds16(pa,       bufn + Q_A + (wid * 2 + 0) * 512);
                gload_lds16(pa + SIB, bufn + Q_A + (wid * 2 + 1) * 512);
                gload_lds16(pb,       bufn + Q_B + (wid * 2 + 0) * 512);
                gload_lds16(pb + SIB, bufn + Q_B + (wid * 2 + 1) * 512);
                asm volatile("s_waitcnt vmcnt(4)" ::: "memory");   // this step's buf ready; 4 fly
            } else {
                asm volatile("s_waitcnt vmcnt(0)" ::: "memory");
            }
            __builtin_amdgcn_s_barrier();

            // fragment reads — compiler schedules counted lgkmcnt vs MFMA
            half8 ah[4], bh[4];
#pragma unroll
            for (int i = 0; i < 4; ++i)
                ah[i] = *(const half8*)(bufc + Q_A + (wm * 4 + i) * 512 + fragoff);
#pragma unroll
            for (int j = 0; j < 4; ++j)
                bh[j] = *(const half8*)(bufc + Q_B + (wn * 4 + j) * 512 + fragoff);

            __builtin_amdgcn_s_setprio(1);
#pragma unroll
            for (int i = 0; i < 4; ++i)
#pragma unroll
                for (int j = 0; j < 4; ++j)
                    acc[i][j] = __builtin_amdgcn_mfma_f32_16x16x32_f16(ah[i], bh[j], acc[i][j], 0, 0, 0);
            __builtin_amdgcn_s_setprio(0);

            asm volatile("" ::: "memory");
            __builtin_amdgcn_s_barrier();      // readers done -> bufc may be re-staged
        }

        // ---- per-chunk argmin epilogue (chunk = 128 cols)
#pragma unroll
        for (int i = 0; i < 4; ++i)
#pragma unroll
            for (int r = 0; r < 4; ++r) {
                float m1 = 3.4e38f, m2 = 3.4e38f;
                int   i1 = 0;
#pragma unroll
                for (int j = 0; j < 4; ++j) {
                    const float d  = fmaf(-2.0f, acc[i][j][r], cn4[j]);
                    const int   ix = kb0 + colw + j * 16 + l15;
                    if (d < m1) { m2 = m1; m1 = d; i1 = ix; }
                    else if (d < m2) { m2 = d; }
                }
#pragma unroll
                for (int off = 1; off < 16; off <<= 1) {
                    const float om1 = __shfl_xor(m1, off, 64);
                    const int   oi  = __shfl_xor(i1, off, 64);
                    const float om2 = __shfl_xor(m2, off, 64);
                    const float nm2 = fminf(fminf(m2, om2), fmaxf(m1, om1));
                    if (om1 < m1 || (om1 == m1 && oi < i1)) { m1 = om1; i1 = oi; }
                    m2 = nm2;
                }
                if (l15 == 0) {
                    const int rr = i * 16 + l4 * 4 + r;
                    red_d[wm][rr][wn] = m1;
                    red_i[wm][rr][wn] = i1;
                    red_2[wm][rr][wn] = m2;
                }
            }
        asm volatile("s_waitcnt lgkmcnt(0)" ::: "memory");
        __builtin_amdgcn_s_barrier();
        __builtin_amdgcn_sched_barrier(0);

        if (tid < 128) {
            const int h2 = tid >> 6;
            const int r2 = tid & 63;
            float m1 = red_d[h2][r2][0], m2 = red_2[h2][r2][0];
            int   i1 = red_i[h2][r2][0];
            const float om1 = red_d[h2][r2][1];
            const int   oi  = red_i[h2][r2][1];
            const float om2 = red_2[h2][r2][1];
            m2 = fminf(fminf(m2, om2), fmaxf(m1, om1));
            if (om1 < m1 || (om1 == m1 && oi < i1)) { m1 = om1; i1 = oi; }
            const float nm2 = fminf(fminf(rm2, m2), fmaxf(rm1, m1));
            if (m1 < rm1 || (m1 == rm1 && i1 < ri1)) { rm1 = m1; ri1 = i1; }
            rm2 = nm2;
        }
        // red re-written only after the next chunk's 64 step-barriers -> safe

#pragma unroll
        for (int i = 0; i < 4; ++i)
#pragma unroll
            for (int j = 0; j < 4; ++j) acc[i][j] = (floatx4)0.0f;
    }

    if (tid < 128) {
        const size_t off = (size_t)ks * N_ROWS + row0 + tid;
        m1buf[off] = rm1;
        i1buf[off] = ri1;
        m2buf[off] = rm2;
    }
}

// ============================================================================
// Merge K-slices: final argmin + certainty test + worklist
// ============================================================================
__global__ __launch_bounds__(256) void kmeans_merge4(
    const float* __restrict__ m1buf, const int* __restrict__ i1buf,
    const float* __restrict__ m2buf, int* __restrict__ out,
    int* __restrict__ urows, unsigned int* __restrict__ ucount)
{
    const int row = blockIdx.x * 256 + threadIdx.x;
    float m1 = m1buf[row], m2 = m2buf[row];
    int   i1 = i1buf[row];
#pragma unroll
    for (int s = 1; s < KSL; ++s) {
        const float om1 = m1buf[(size_t)s * N_ROWS + row];
        const float om2 = m2buf[(size_t)s * N_ROWS + row];
        const int   oi  = i1buf[(size_t)s * N_ROWS + row];
        const float nm2 = fminf(fminf(m2, om2), fmaxf(m1, om1));
        if (om1 < m1 || (om1 == m1 && oi < i1)) { m1 = om1; i1 = oi; }
        m2 = nm2;
    }
    out[row] = i1;
    if (m2 - m1 <= EPS_GAP) {
        const unsigned slot = atomicAdd(ucount, 1u);
        if (slot < (unsigned)CAP) urows[slot] = row;
    }
}

// ============================================================================
// Gather: uncertain rows' x -> compact fp16 hi/lo buffers [slot][1024]
// ============================================================================
__global__ __launch_bounds__(64) void kmeans_gather(
    const float* __restrict__ x, const int* __restrict__ urows,
    const unsigned int* __restrict__ ucount,
    _Float16* __restrict__ xch, _Float16* __restrict__ xcl)
{
    const unsigned cntr = *ucount;
    const unsigned cnt = cntr > (unsigned)CAP ? (unsigned)CAP : cntr;
    const unsigned slot = blockIdx.x;
    if (slot >= cnt) return;
    const int row = urows[slot];
    const int t = threadIdx.x;
#pragma unroll
    for (int e = 0; e < 16; ++e) {
        const int idx = e * 64 + t;
        const float v = x[(size_t)row * D_DIM + idx];
        const _Float16 h = (_Float16)v;
        xch[(size_t)slot * D_DIM + idx] = h;
        xcl[(size_t)slot * D_DIM + idx] = (_Float16)(v - (float)h);
    }
}

// ============================================================================
// Rescore (K-split x8): exact 3-pass hi/lo over 512-col slice for 32 rows.
// ============================================================================
constexpr int R_XH = 0;        // 1024 halves (2 sub)
constexpr int R_XL = 1024;     // 1024
constexpr int R_CH = 2048;     // 8192 (16 sub)
constexpr int R_CL = 10240;    // 8192
constexpr int R_HB = 18432;    // per buffer (36 KB)

__global__ __launch_bounds__(256) void kmeans_rescore2(
    const _Float16* __restrict__ xch, const _Float16* __restrict__ xcl,
    const _Float16* __restrict__ ChiT, const _Float16* __restrict__ CloT,
    const float* __restrict__ Cnorm, const unsigned int* __restrict__ ucount,
    float* __restrict__ rpd, int* __restrict__ rpi)
{
    const unsigned cntr = *ucount;
    const unsigned cnt = cntr > (unsigned)CAP ? (unsigned)CAP : cntr;
    const int bid = blockIdx.x;
    const int ksl = bid & 7;
    const int grp = bid >> 3;
    if ((unsigned)(grp * 32) >= cnt) return;

    __shared__ _Float16 lds[2][R_HB];
    __shared__ float rd[32][4];
    __shared__ int   ri[32][4];

    const int tid  = threadIdx.x;
    const int lane = tid & 63;
    const int wid  = tid >> 6;
    const int l15  = lane & 15;
    const int l4   = lane >> 4;
    const int kge  = l4 ^ ((l15 >> 1) & 3);
    const int fragoff = l15 * 32 + kge * 8;
    const int scol = lane >> 2;
    const int skg  = (lane & 3) ^ ((scol >> 1) & 3);

    const int base  = grp * 32;
    const int kbase = ksl * (K_CENT / RSL);

    float best[2][4];
    int   bidx[2][4];
#pragma unroll
    for (int i = 0; i < 2; ++i)
#pragma unroll
        for (int r = 0; r < 4; ++r) { best[i][r] = 3.4e38f; bidx[i][r] = 0; }

    for (int ch = 0; ch < 2; ++ch) {
        const int kc = kbase + ch * 256;
        floatx4 acc[2][4];
#pragma unroll
        for (int i = 0; i < 2; ++i)
#pragma unroll
            for (int j = 0; j < 4; ++j) acc[i][j] = (floatx4)0.0f;

        {
            _Float16* buf = lds[0];
#pragma unroll
            for (int q = 0; q < 4; ++q) {
                const int sub = wid * 4 + q;
                gload_lds16(&ChiT[(size_t)(kc + sub * 16 + scol) * D_DIM + 0 + skg * 8], buf + R_CH + sub * 512);
                gload_lds16(&CloT[(size_t)(kc + sub * 16 + scol) * D_DIM + 0 + skg * 8], buf + R_CL + sub * 512);
            }
            if (wid < 2)
                gload_lds16(&xch[(size_t)(base + wid * 16 + scol) * D_DIM + 0 + skg * 8], buf + R_XH + wid * 512);
            else
                gload_lds16(&xcl[(size_t)(base + (wid - 2) * 16 + scol) * D_DIM + 0 + skg * 8], buf + R_XL + (wid - 2) * 512);
            __syncthreads();
        }

        for (int kdi = 0; kdi < D_DIM / 32; ++kdi) {
            const int cur = kdi & 1;
            _Float16* bufc = lds[cur];
            _Float16* bufn = lds[cur ^ 1];
            const int  kdn = (kdi + 1) * 32;
            const bool pf  = (kdi + 1 < D_DIM / 32);

            if (pf) {
#pragma unroll
                for (int q = 0; q < 4; ++q) {
                    const int sub = wid * 4 + q;
                    gload_lds16(&ChiT[(size_t)(kc + sub * 16 + scol) * D_DIM + kdn + skg * 8], bufn + R_CH + sub * 512);
                    gload_lds16(&CloT[(size_t)(kc + sub * 16 + scol) * D_DIM + kdn + skg * 8], bufn + R_CL + sub * 512);
                }
                if (wid < 2)
                    gload_lds16(&xch[(size_t)(base + wid * 16 + scol) * D_DIM + kdn + skg * 8], bufn + R_XH + wid * 512);
                else
                    gload_lds16(&xcl[(size_t)(base + (wid - 2) * 16 + scol) * D_DIM + kdn + skg * 8], bufn + R_XL + (wid - 2) * 512);
            }

            half8 ah[2], al[2], bh[4], bl[4];
#pragma unroll
            for (int i = 0; i < 2; ++i) {
                ah[i] = *(const half8*)(bufc + R_XH + i * 512 + fragoff);
                al[i] = *(const half8*)(bufc + R_XL + i * 512 + fragoff);
            }
#pragma unroll
            for (int j = 0; j < 4; ++j) {
                bh[j] = *(const half8*)(bufc + R_CH + (wid * 4 + j) * 512 + fragoff);
                bl[j] = *(const half8*)(bufc + R_CL + (wid * 4 + j) * 512 + fragoff);
            }
#pragma unroll
            for (int i = 0; i < 2; ++i)
#pragma unroll
                for (int j = 0; j < 4; ++j) {
                    acc[i][j] = __builtin_amdgcn_mfma_f32_16x16x32_f16(ah[i], bh[j], acc[i][j], 0, 0, 0);
                    acc[i][j] = __builtin_amdgcn_mfma_f32_16x16x32_f16(ah[i], bl[j], acc[i][j], 0, 0, 0);
                    acc[i][j] = __builtin_amdgcn_mfma_f32_16x16x32_f16(al[i], bh[j], acc[i][j], 0, 0, 0);
                }
            __syncthreads();
        }

#pragma unroll
        for (int j = 0; j < 4; ++j) {
            const int col = kc + wid * 64 + j * 16 + l15;
            const float cn = Cnorm[col];
#pragma unroll
            for (int i = 0; i < 2; ++i)
#pragma unroll
                for (int r = 0; r < 4; ++r) {
                    const float d = fmaf(-2.0f, acc[i][j][r], cn);
                    if (d < best[i][r]) { best[i][r] = d; bidx[i][r] = col; }
                }
        }
    }

#pragma unroll
    for (int i = 0; i < 2; ++i)
#pragma unroll
        for (int r = 0; r < 4; ++r) {
            float m1 = best[i][r];
            int   i1 = bidx[i][r];
#pragma unroll
            for (int off = 1; off < 16; off <<= 1) {
                const float om1 = __shfl_xor(m1, off, 64);
                const int   oi  = __shfl_xor(i1, off, 64);
                if (om1 < m1 || (om1 == m1 && oi < i1)) { m1 = om1; i1 = oi; }
            }
            if (l15 == 0) { rd[i * 16 + l4 * 4 + r][wid] = m1; ri[i * 16 + l4 * 4 + r][wid] = i1; }
        }
    __syncthreads();

    if (tid < 32) {
        float m1 = rd[tid][0];
        int   i1 = ri[tid][0];
#pragma unroll
        for (int w = 1; w < 4; ++w) {
            const float om1 = rd[tid][w];
            const int   oi  = ri[tid][w];
            if (om1 < m1 || (om1 == m1 && oi < i1)) { m1 = om1; i1 = oi; }
        }
        rpd[(size_t)(base + tid) * RSL + ksl] = m1;
        rpi[(size_t)(base + tid) * RSL + ksl] = i1;
    }
}

// ============================================================================
// Merge rescore slices -> final out for uncertain rows
// ============================================================================
__global__ __launch_bounds__(256) void kmeans_merge2(
    const float* __restrict__ rpd, const int* __restrict__ rpi,
    const int* __restrict__ urows, const unsigned int* __restrict__ ucount,
    int* __restrict__ out)
{
    const unsigned cntr = *ucount;
    const unsigned cnt = cntr > (unsigned)CAP ? (unsigned)CAP : cntr;
    const unsigned s = blockIdx.x * 256 + threadIdx.x;
    if (s >= cnt) return;
    float m1 = rpd[(size_t)s * RSL];
    int   i1 = rpi[(size_t)s * RSL];
#pragma unroll
    for (int k = 1; k < RSL; ++k) {
        const float om = rpd[(size_t)s * RSL + k];
        const int   oi = rpi[(size_t)s * RSL + k];
        if (om < m1 || (om == m1 && oi < i1)) { m1 = om; i1 = oi; }
    }
    out[urows[s]] = i1;
}

// ============================================================================
// Fallback A: proven R3 3-pass MFMA kernel (hi/lo, direct out)
// ============================================================================
constexpr int F_XH = 0, F_XL = 4096, F_CH = 8192, F_CL = 16384, F_HB = 24576;

__device__ __forceinline__ void write_x2(_Float16* buf, const float4 v, int r, int kb) {
    const _Float16 h0 = (_Float16)v.x, h1 = (_Float16)v.y;
    const _Float16 h2 = (_Float16)v.z, h3 = (_Float16)v.w;
    const int kg  = kb >> 3;
    const int hs  = (kb >> 2) & 1;
    const int kge = kg ^ ((r >> 1) & 3);
    const int base = (r >> 4) * 512 + (r & 15) * 32 + kge * 8 + hs * 4;
    *(half4*)(buf + F_XH + base) = (half4){h0, h1, h2, h3};
    *(half4*)(buf + F_XL + base) = (half4){(_Float16)(v.x - (float)h0), (_Float16)(v.y - (float)h1),
                                           (_Float16)(v.z - (float)h2), (_Float16)(v.w - (float)h3)};
}

__global__ __launch_bounds__(512, 2) void kmeans_mfma_kernel(
    const float* __restrict__ x, const _Float16* __restrict__ ChiT,
    const _Float16* __restrict__ CloT, const float* __restrict__ Cnorm,
    int* __restrict__ out)
{
    __shared__ _Float16 lds[2][F_HB];
    __shared__ float red_d[2][64][4];
    __shared__ int   red_i[2][64][4];

    const int tid  = threadIdx.x;
    const int lane = tid & 63;
    const int wid  = tid >> 6;
    const int wm   = wid >> 2;
    const int wn   = wid & 3;
    const int row0 = blockIdx.x * 128;
    const int l15 = lane & 15;
    const int l4  = lane >> 4;
    const int kge = l4 ^ ((l15 >> 1) & 3);
    const int fragoff = l15 * 32 + kge * 8;
    const int sr = tid >> 2, sc = tid & 3;
    const int ccol = lane >> 2;
    const int ckg  = (lane & 3) ^ ((ccol >> 1) & 3);

    float best[4][4];
    int   bidx[4][4];
#pragma unroll
    for (int i = 0; i < 4; ++i)
#pragma unroll
        for (int r = 0; r < 4; ++r) { best[i][r] = 3.4e38f; bidx[i][r] = 0; }

    for (int kc = 0; kc < K_CENT; kc += 256) {
        floatx4 acc[4][4];
#pragma unroll
        for (int i = 0; i < 4; ++i)
#pragma unroll
            for (int j = 0; j < 4; ++j) acc[i][j] = (floatx4)0.0f;
        {
            _Float16* buf = lds[0];
            const float4 xv0 = *(const float4*)&x[(size_t)(row0 + sr) * D_DIM + 0 + sc * 4];
            const float4 xv1 = *(const float4*)&x[(size_t)(row0 + sr) * D_DIM + 16 + sc * 4];
            gload_lds16(&ChiT[(size_t)(kc + wid * 16 + ccol) * D_DIM + 0 + ckg * 8], buf + F_CH + wid * 512);
            gload_lds16(&ChiT[(size_t)(kc + (wid + 8) * 16 + ccol) * D_DIM + 0 + ckg * 8], buf + F_CH + (wid + 8) * 512);
            gload_lds16(&CloT[(size_t)(kc + wid * 16 + ccol) * D_DIM + 0 + ckg * 8], buf + F_CL + wid * 512);
            gload_lds16(&CloT[(size_t)(kc + (wid + 8) * 16 + ccol) * D_DIM + 0 + ckg * 8], buf + F_CL + (wid + 8) * 512);
            write_x2(buf, xv0, sr, sc * 4);
            write_x2(buf, xv1, sr, sc * 4 + 16);
            __syncthreads();
        }
        for (int kdi = 0; kdi < D_DIM / 32; ++kdi) {
            const int cur = kdi & 1;
            _Float16* bufc = lds[cur];
            _Float16* bufn = lds[cur ^ 1];
            const int  kdn = (kdi + 1) * 32;
            const bool pf  = (kdi + 1 < D_DIM / 32);
            float4 xv0, xv1;
            if (pf) {
                xv0 = *(const float4*)&x[(size_t)(row0 + sr) * D_DIM + kdn + sc * 4];
                xv1 = *(const float4*)&x[(size_t)(row0 + sr) * D_DIM + kdn + 16 + sc * 4];
                gload_lds16(&ChiT[(size_t)(kc + wid * 16 + ccol) * D_DIM + kdn + ckg * 8], bufn + F_CH + wid * 512);
                gload_lds16(&ChiT[(size_t)(kc + (wid + 8) * 16 + ccol) * D_DIM + kdn + ckg * 8], bufn + F_CH + (wid + 8) * 512);
                gload_lds16(&CloT[(size_t)(kc + wid * 16 + ccol) * D_DIM + kdn + ckg * 8], bufn + F_CL + wid * 512);
                gload_lds16(&CloT[(size_t)(kc + (wid + 8) * 16 + ccol) * D_DIM + kdn + ckg * 8], bufn + F_CL + (wid + 8) * 512);
            }
            half8 ah[4], al[4], bh[4], bl[4];
#pragma unroll
            for (int i = 0; i < 4; ++i) {
                ah[i] = *(const half8*)(bufc + F_XH + (wm * 4 + i) * 512 + fragoff);
                al[i] = *(const half8*)(bufc + F_XL + (wm * 4 + i) * 512 + fragoff);
            }
#pragma unroll
            for (int j = 0; j < 4; ++j) {
                bh[j] = *(const half8*)(bufc + F_CH + (wn * 4 + j) * 512 + fragoff);
                bl[j] = *(const half8*)(bufc + F_CL + (wn * 4 + j) * 512 + fragoff);
            }
#pragma unroll
            for (int i = 0; i < 4; ++i)
#pragma unroll
                for (int j = 0; j < 4; ++j) {
                    acc[i][j] = __builtin_amdgcn_mfma_f32_16x16x32_f16(ah[i], bh[j], acc[i][j], 0, 0, 0);
                    acc[i][j] = __builtin_amdgcn_mfma_f32_16x16x32_f16(ah[i], bl[j], acc[i][j], 0, 0, 0);
                    acc[i][j] = __builtin_amdgcn_mfma_f32_16x16x32_f16(al[i], bh[j], acc[i][j], 0, 0, 0);
                }
            if (pf) {
                write_x2(bufn, xv0, sr, sc * 4);
                write_x2(bufn, xv1, sr, sc * 4 + 16);
            }
            __syncthreads();
        }
        const int colw = kc + wn * 64;
#pragma unroll
        for (int ns = 0; ns < 4; ++ns) {
            const float cn = Cnorm[colw + ns * 16 + l15];
            const int   ix = colw + ns * 16 + l15;
#pragma unroll
            for (int i = 0; i < 4; ++i)
#pragma unroll
                for (int r = 0; r < 4; ++r) {
                    const float d = fmaf(-2.0f, acc[i][ns][r], cn);
                    if (d < best[i][r]) { best[i][r] = d; bidx[i][r] = ix; }
                }
        }
    }
#pragma unroll
    for (int i = 0; i < 4; ++i)
#pragma unroll
        for (int r = 0; r < 4; ++r) {
            float d  = best[i][r];
            int   ix = bidx[i][r];
#pragma unroll
            for (int off = 1; off < 16; off <<= 1) {
                const float od = __shfl_xor(d, off, 64);
                const int   oi = __shfl_xor(ix, off, 64);
                if (od < d || (od == d && oi < ix)) { d = od; ix = oi; }
            }
            if (l15 == 0) {
                red_d[wm][i * 16 + l4 * 4 + r][wn] = d;
                red_i[wm][i * 16 + l4 * 4 + r][wn] = ix;
            }
        }
    __syncthreads();
    if (tid < 128) {
        const int hh = tid >> 6, rr = tid & 63;
        float bd = red_d[hh][rr][0];
        int   bi2 = red_i[hh][rr][0];
#pragma unroll
        for (int w = 1; w < 4; ++w) {
            const float od = red_d[hh][rr][w];
            const int   oi = red_i[hh][rr][w];
            if (od < bd || (od == bd && oi < bi2)) { bd = od; bi2 = oi; }
        }
        out[row0 + tid] = bi2;
    }
}

// ============================================================================
// Fallback B: R1 fp32 kernel
// ============================================================================
__global__ __launch_bounds__(256, 2) void kmeans_assign_f32(
    const float* __restrict__ x, const float* __restrict__ Cm,
    const float* __restrict__ Cnorm, int* __restrict__ out)
{
    __shared__ float xs[32][64];
    __shared__ float cs[32][64];
    const int tid = threadIdx.x;
    const int tx = tid & 15, ty = tid >> 4;
    const int row0 = blockIdx.x * 64;
    const int xr = tid >> 3, xc = tid & 7;
    const int cr = tid >> 4, cc = tid & 15;
    float best[4]; int bidx[4];
#pragma unroll
    for (int i = 0; i < 4; ++i) { best[i] = 3.4e38f; bidx[i] = 0; }
    for (int kc = 0; kc < K_CENT; kc += 64) {
        float acc[16];
#pragma unroll
        for (int i = 0; i < 16; ++i) acc[i] = 0.0f;
        for (int kd = 0; kd < D_DIM; kd += 32) {
            const float4 xv0 = *(const float4*)&x[(size_t)(row0 + xr) * D_DIM + kd + xc * 4];
            const float4 xv1 = *(const float4*)&x[(size_t)(row0 + xr + 32) * D_DIM + kd + xc * 4];
            const float4 cv0 = *(const float4*)&Cm[(size_t)(kd + cr) * K_CENT + kc + cc * 4];
            const float4 cv1 = *(const float4*)&Cm[(size_t)(kd + cr + 16) * K_CENT + kc + cc * 4];
            __syncthreads();
            xs[xc*4+0][xr] = xv0.x; xs[xc*4+1][xr] = xv0.y; xs[xc*4+2][xr] = xv0.z; xs[xc*4+3][xr] = xv0.w;
            xs[xc*4+0][xr+32] = xv1.x; xs[xc*4+1][xr+32] = xv1.y; xs[xc*4+2][xr+32] = xv1.z; xs[xc*4+3][xr+32] = xv1.w;
            *(float4*)&cs[cr][cc*4]    = cv0;
            *(float4*)&cs[cr+16][cc*4] = cv1;
            __syncthreads();
#pragma unroll
            for (int kk = 0; kk < 32; ++kk) {
                const float4 a = *(const float4*)&xs[kk][ty*4];
                const float4 b = *(const float4*)&cs[kk][tx*4];
                acc[ 0] += a.x*b.x; acc[ 1] += a.x*b.y; acc[ 2] += a.x*b.z; acc[ 3] += a.x*b.w;
                acc[ 4] += a.y*b.x; acc[ 5] += a.y*b.y; acc[ 6] += a.y*b.z; acc[ 7] += a.y*b.w;
                acc[ 8] += a.z*b.x; acc[ 9] += a.z*b.y; acc[10] += a.z*b.z; acc[11] += a.z*b.w;
                acc[12] += a.w*b.x; acc[13] += a.w*b.y; acc[14] += a.w*b.z; acc[15] += a.w*b.w;
            }
        }
        const float4 cn = *(const float4*)&Cnorm[kc + tx*4];
        const float cnv[4] = {cn.x, cn.y, cn.z, cn.w};
#pragma unroll
        for (int i = 0; i < 4; ++i)
#pragma unroll
            for (int j = 0; j < 4; ++j) {
                const float dist = cnv[j] - 2.0f * acc[i*4+j];
                const int   idx  = kc + tx*4 + j;
                if (dist < best[i]) { best[i] = dist; bidx[i] = idx; }
            }
    }
#pragma unroll
    for (int i = 0; i < 4; ++i) {
        float d = best[i]; int ix = bidx[i];
#pragma unroll
        for (int off = 1; off < 16; off <<= 1) {
            const float od = __shfl_xor(d, off, 64);
            const int   oi = __shfl_xor(ix, off, 64);
            if (od < d || (od == d && oi < ix)) { d = od; ix = oi; }
        }
        if (tx == 0) out[row0 + ty*4 + i] = ix;
    }
}

// ============================================================================
extern "C" void kernel_launch(void* const* d_in, const int* in_sizes, int n_in,
                              void* d_out, int out_size, void* d_ws, size_t ws_size,
                              hipStream_t stream) {
    const float* x     = (const float*)d_in[0];
    const float* C     = (const float*)d_in[1];
    const float* Cnorm = (const float*)d_in[2];
    int* out = (int*)d_out;

    const size_t chalf = (size_t)K_CENT * D_DIM;   // halves per C array
    const size_t capd  = (size_t)CAP * D_DIM;      // halves per xc array
    const size_t xhN   = (size_t)N_ROWS * D_DIM;   // halves for x_hi

    const size_t sz_base = (2 * chalf + 2 * capd) * 2
                         + (size_t)KSL * N_ROWS * 12
                         + (size_t)CAP * RSL * 8
                         + (size_t)CAP * 4 + 64;
    const size_t need_full = sz_base + xhN * 2;
    const size_t need_r3   = 2 * chalf * 2;

    if (ws_size >= need_full) {
        _Float16* ChiT = (_Float16*)d_ws;
        _Float16* CloT = ChiT + chalf;
        _Float16* xch  = CloT + chalf;
        _Float16* xcl  = xch + capd;
        float* m1buf = (float*)(xcl + capd);
        float* m2buf = m1buf + (size_t)KSL * N_ROWS;
        int*   i1buf = (int*)(m2buf + (size_t)KSL * N_ROWS);
        float* rpd   = (float*)(i1buf + (size_t)KSL * N_ROWS);
        int*   rpi   = (int*)(rpd + (size_t)CAP * RSL);
        int*   urows = rpi + (size_t)CAP * RSL;
        unsigned int* ucount = (unsigned int*)(urows + CAP);
        _Float16* xh = (_Float16*)(ucount + 16);

        convert_C_kernel<<<dim3(128, 32), 256, 0, stream>>>(C, ChiT, CloT);
        convert_x_kernel<<<dim3((int)(xhN / 2048)), 256, 0, stream>>>(x, xh);
        hipMemsetAsync(ucount, 0, sizeof(unsigned int), stream);
        kmeans_pass1<<<dim3(256 * KSL), 256, 0, stream>>>(xh, ChiT, Cnorm, m1buf, i1buf, m2buf);
        kmeans_merge4<<<dim3(N_ROWS / 256), 256, 0, stream>>>(m1buf, i1buf, m2buf, out, urows, ucount);
        kmeans_gather<<<dim3(CAP), 64, 0, stream>>>(x, urows, ucount, xch, xcl);
        kmeans_rescore2<<<dim3((CAP / 32) * RSL), 256, 0, stream>>>(xch, xcl, ChiT, CloT, Cnorm, ucount, rpd, rpi);
        kmeans_merge2<<<dim3(CAP / 256), 256, 0, stream>>>(rpd, rpi, urows, ucount, out);
    } else if (ws_size >= need_r3) {
        _Float16* ChiT = (_Float16*)d_ws;
        _Float16* CloT = ChiT + chalf;
        convert_C_kernel<<<dim3(128, 32), 256, 0, stream>>>(C, ChiT, CloT);
        kmeans_mfma_kernel<<<dim3(N_ROWS / 128), 512, 0, stream>>>(x, ChiT, CloT, Cnorm, out);
    } else {
        kmeans_assign_f32<<<dim3(N_ROWS / 64), 256, 0, stream>>>(x, C, Cnorm, out);
    }
}

// Round 14
// 491.871 us; speedup vs baseline: 2.1932x; 1.0118x over previous
//
#include <hip/hip_runtime.h>
#include <cstdint>
#include <cstddef>

typedef _Float16 half8 __attribute__((ext_vector_type(8)));
typedef _Float16 half4 __attribute__((ext_vector_type(4)));
typedef float    floatx4 __attribute__((ext_vector_type(4)));

constexpr int N_ROWS = 32768;
constexpr int D_DIM  = 1024;
constexpr int K_CENT = 4096;
constexpr int CAP    = 4096;      // max uncertain rows (E[count]~620)
constexpr int KSL    = 4;         // pass1 K split (1024 cols/slice)
constexpr int RSL    = 8;         // rescore K split (512 cols/slice)
constexpr float EPS_GAP = 0.4f;   // 2 * (14-sigma hh-error bound)

__device__ __forceinline__ void gload_lds16(const void* g, void* l) {
    __builtin_amdgcn_global_load_lds(
        (const __attribute__((address_space(1))) uint32_t*)g,
        (__attribute__((address_space(3))) uint32_t*)l, 16, 0, 0);
}

// ============================================================================
// Fused pre-pass: C split-transpose + x -> fp16 + ucount reset.  One launch.
//   bid < 4096   : C[d][k] f32 -> C_hiT[k][d], C_loT[k][d]  (bk=bid&127, bd=bid>>7)
//   bid >= 4096  : x f32 -> x_hi fp16 (elementwise, 2048 elems/block)
// ============================================================================
__global__ __launch_bounds__(256) void convert_all(
    const float* __restrict__ C, const float* __restrict__ x,
    _Float16* __restrict__ ChiT, _Float16* __restrict__ CloT,
    _Float16* __restrict__ xh, unsigned int* __restrict__ ucount)
{
    const int bid = blockIdx.x;
    const int t   = threadIdx.x;
    if (bid == 0 && t == 0) *ucount = 0;

    if (bid < 4096) {
        __shared__ float tile[32][33];
        const int bk = bid & 127, bd = bid >> 7;
        const int r = t >> 3, c4 = (t & 7) * 4;
        const float4 v = *(const float4*)&C[(size_t)(bd * 32 + r) * K_CENT + bk * 32 + c4];
        tile[r][c4 + 0] = v.x; tile[r][c4 + 1] = v.y;
        tile[r][c4 + 2] = v.z; tile[r][c4 + 3] = v.w;
        __syncthreads();
        half4 h, l;
#pragma unroll
        for (int i = 0; i < 4; ++i) {
            const float f = tile[c4 + i][r];
            const _Float16 hi = (_Float16)f;
            h[i] = hi;
            l[i] = (_Float16)(f - (float)hi);
        }
        *(half4*)&ChiT[(size_t)(bk * 32 + r) * D_DIM + bd * 32 + c4] = h;
        *(half4*)&CloT[(size_t)(bk * 32 + r) * D_DIM + bd * 32 + c4] = l;
    } else {
        const size_t g = (size_t)(bid - 4096) * 256 + t;   // 8 elems each
        const float4 v0 = *(const float4*)&x[g * 8];
        const float4 v1 = *(const float4*)&x[g * 8 + 4];
        half8 h;
        h[0] = (_Float16)v0.x; h[1] = (_Float16)v0.y; h[2] = (_Float16)v0.z; h[3] = (_Float16)v0.w;
        h[4] = (_Float16)v1.x; h[5] = (_Float16)v1.y; h[6] = (_Float16)v1.z; h[7] = (_Float16)v1.w;
        *(half8*)&xh[g * 8] = h;
    }
}

// ============================================================================
// Pass 1 (FROZEN from R13, best measured: ~412us, MfmaUtil 30%, occ 44%):
// hh-only GEMM, 128x128 block tile, 256 thr / 4 waves (2x2), per-wave 64x64
// (acc[4][4]), BK=32, 2-buffer dbuf, counted vmcnt(4), pointer-increment
// staging.  KSL=4 -> grid 1024 = 4 blocks/CU; 16 waves/CU.  XCD-bijective.
// ============================================================================
constexpr int Q_A  = 0;        // A subtiles: 8 x 512 halves (x_hi rows)
constexpr int Q_B  = 4096;     // B subtiles: 8 x 512 halves (C_hi cols)
constexpr int Q_HB = 8192;     // 16 KB per buffer

__global__ __launch_bounds__(256, 4) void kmeans_pass1(
    const _Float16* __restrict__ xh, const _Float16* __restrict__ ChiT,
    const float* __restrict__ Cnorm,
    float* __restrict__ m1buf, int* __restrict__ i1buf, float* __restrict__ m2buf)
{
    __shared__ _Float16 lds[2][Q_HB];      // 32 KB
    __shared__ float red_d[2][64][2];
    __shared__ int   red_i[2][64][2];
    __shared__ float red_2[2][64][2];

    // bijective: xcd = bid&7; ks = xcd&3; rb = (bid>>3)*2 + (xcd>>2)  (1024 blocks)
    const int bid  = blockIdx.x;
    const int xcd  = bid & 7;
    const int ks   = xcd & 3;
    const int rb   = (bid >> 3) * 2 + (xcd >> 2);   // 0..255
    const int row0 = rb * 128;
    const int kb0  = ks * (K_CENT / KSL);

    const int tid  = threadIdx.x;
    const int lane = tid & 63;
    const int wid  = tid >> 6;          // 0..3
    const int wm   = wid >> 1;          // 0..1 (64-row half)
    const int wn   = wid & 1;           // 0..1 (64-col half)

    const int l15 = lane & 15;
    const int l4  = lane >> 4;
    const int kge = l4 ^ ((l15 >> 1) & 3);
    const int fragoff = l15 * 32 + kge * 8;

    const int scol = lane >> 2;                       // 0..15
    const int skg  = (lane & 3) ^ ((scol >> 1) & 3);  // pre-swizzled source kg

    // staging pointers: point at the most recently staged (kd) position
    const _Float16* pa = xh   + (size_t)(row0 + (wid * 2) * 16 + scol) * D_DIM + skg * 8;
    const _Float16* pb = ChiT + (size_t)(kb0  + (wid * 2) * 16 + scol) * D_DIM + skg * 8;
    constexpr ptrdiff_t SIB = (ptrdiff_t)16 * D_DIM;  // sibling subtile (+16 rows)

    float rm1 = 3.4e38f, rm2 = 3.4e38f;
    int   ri1 = 0;

    constexpr int NCH = (K_CENT / KSL) / 128;   // 8 chunks of 128 cols

    // prologue: stage chunk0/kd0 into buf 0 (4 loads/wave in flight)
    gload_lds16(pa,       lds[0] + Q_A + (wid * 2 + 0) * 512);
    gload_lds16(pa + SIB, lds[0] + Q_A + (wid * 2 + 1) * 512);
    gload_lds16(pb,       lds[0] + Q_B + (wid * 2 + 0) * 512);
    gload_lds16(pb + SIB, lds[0] + Q_B + (wid * 2 + 1) * 512);

    floatx4 acc[4][4];
#pragma unroll
    for (int i = 0; i < 4; ++i)
#pragma unroll
        for (int j = 0; j < 4; ++j) acc[i][j] = (floatx4)0.0f;

    for (int ci = 0; ci < NCH; ++ci) {
        // hoist this chunk's Cnorm values (retire long before the epilogue)
        const int colw = ci * 128 + wn * 64;
        float cn4[4];
#pragma unroll
        for (int j = 0; j < 4; ++j) cn4[j] = Cnorm[kb0 + colw + j * 16 + l15];

#pragma unroll 2
        for (int kdi = 0; kdi < 32; ++kdi) {
            _Float16* bufc = lds[kdi & 1];
            _Float16* bufn = lds[(kdi + 1) & 1];
            const bool last = (kdi == 31) && (ci == NCH - 1);
            if (!last) {
                if (kdi < 31) { pa += 32;  pb += 32; }
                else          { pa -= 992; pb += 130080; }   // next chunk: kd->0, B rows +128
                gload_lds16(pa,       bufn + Q_A + (wid * 2 + 0) * 512);
                gload_lds16(pa + SIB, bufn + Q_A + (wid * 2 + 1) * 512);
                gload_lds16(pb,       bufn + Q_B + (wid * 2 + 0) * 512);
                gload_lds16(pb + SIB, bufn + Q_B + (wid * 2 + 1) * 512);
                asm volatile("s_waitcnt vmcnt(4)" ::: "memory");   // this step's buf ready; 4 fly
            } else {
                asm volatile("s_waitcnt vmcnt(0)" ::: "memory");
            }
            __builtin_amdgcn_s_barrier();

            // fragment reads — compiler schedules counted lgkmcnt vs MFMA
            half8 ah[4], bh[4];
#pragma unroll
            for (int i = 0; i < 4; ++i)
                ah[i] = *(const half8*)(bufc + Q_A + (wm * 4 + i) * 512 + fragoff);
#pragma unroll
            for (int j = 0; j < 4; ++j)
                bh[j] = *(const half8*)(bufc + Q_B + (wn * 4 + j) * 512 + fragoff);

            __builtin_amdgcn_s_setprio(1);
#pragma unroll
            for (int i = 0; i < 4; ++i)
#pragma unroll
                for (int j = 0; j < 4; ++j)
                    acc[i][j] = __builtin_amdgcn_mfma_f32_16x16x32_f16(ah[i], bh[j], acc[i][j], 0, 0, 0);
            __builtin_amdgcn_s_setprio(0);

            asm volatile("" ::: "memory");
            __builtin_amdgcn_s_barrier();      // readers done -> bufc may be re-staged
        }

        // ---- per-chunk argmin epilogue (chunk = 128 cols)
#pragma unroll
        for (int i = 0; i < 4; ++i)
#pragma unroll
            for (int r = 0; r < 4; ++r) {
                float m1 = 3.4e38f, m2 = 3.4e38f;
                int   i1 = 0;
#pragma unroll
                for (int j = 0; j < 4; ++j) {
                    const float d  = fmaf(-2.0f, acc[i][j][r], cn4[j]);
                    const int   ix = kb0 + colw + j * 16 + l15;
                    if (d < m1) { m2 = m1; m1 = d; i1 = ix; }
                    else if (d < m2) { m2 = d; }
                }
#pragma unroll
                for (int off = 1; off < 16; off <<= 1) {
                    const float om1 = __shfl_xor(m1, off, 64);
                    const int   oi  = __shfl_xor(i1, off, 64);
                    const float om2 = __shfl_xor(m2, off, 64);
                    const float nm2 = fminf(fminf(m2, om2), fmaxf(m1, om1));
                    if (om1 < m1 || (om1 == m1 && oi < i1)) { m1 = om1; i1 = oi; }
                    m2 = nm2;
                }
                if (l15 == 0) {
                    const int rr = i * 16 + l4 * 4 + r;
                    red_d[wm][rr][wn] = m1;
                    red_i[wm][rr][wn] = i1;
                    red_2[wm][rr][wn] = m2;
                }
            }
        asm volatile("s_waitcnt lgkmcnt(0)" ::: "memory");
        __builtin_amdgcn_s_barrier();
        __builtin_amdgcn_sched_barrier(0);

        if (tid < 128) {
            const int h2 = tid >> 6;
            const int r2 = tid & 63;
            float m1 = red_d[h2][r2][0], m2 = red_2[h2][r2][0];
            int   i1 = red_i[h2][r2][0];
            const float om1 = red_d[h2][r2][1];
            const int   oi  = red_i[h2][r2][1];
            const float om2 = red_2[h2][r2][1];
            m2 = fminf(fminf(m2, om2), fmaxf(m1, om1));
            if (om1 < m1 || (om1 == m1 && oi < i1)) { m1 = om1; i1 = oi; }
            const float nm2 = fminf(fminf(rm2, m2), fmaxf(rm1, m1));
            if (m1 < rm1 || (m1 == rm1 && i1 < ri1)) { rm1 = m1; ri1 = i1; }
            rm2 = nm2;
        }
        // red re-written only after the next chunk's 64 step-barriers -> safe

#pragma unroll
        for (int i = 0; i < 4; ++i)
#pragma unroll
            for (int j = 0; j < 4; ++j) acc[i][j] = (floatx4)0.0f;
    }

    if (tid < 128) {
        const size_t off = (size_t)ks * N_ROWS + row0 + tid;
        m1buf[off] = rm1;
        i1buf[off] = ri1;
        m2buf[off] = rm2;
    }
}

// ============================================================================
// Fused merge + gather: final argmin per row, certainty test, and inline
// conversion of uncertain rows into compact fp16 hi/lo buffers.
// ============================================================================
__global__ __launch_bounds__(256) void kmeans_merge_gather(
    const float* __restrict__ m1buf, const int* __restrict__ i1buf,
    const float* __restrict__ m2buf, const float* __restrict__ x,
    int* __restrict__ out, int* __restrict__ urows, unsigned int* __restrict__ ucount,
    _Float16* __restrict__ xch, _Float16* __restrict__ xcl)
{
    __shared__ int lrows[256];
    __shared__ int lcnt;
    __shared__ unsigned gbase;

    const int tid = threadIdx.x;
    if (tid == 0) lcnt = 0;
    __syncthreads();

    const int row = blockIdx.x * 256 + tid;
    float m1 = m1buf[row], m2 = m2buf[row];
    int   i1 = i1buf[row];
#pragma unroll
    for (int s = 1; s < KSL; ++s) {
        const float om1 = m1buf[(size_t)s * N_ROWS + row];
        const float om2 = m2buf[(size_t)s * N_ROWS + row];
        const int   oi  = i1buf[(size_t)s * N_ROWS + row];
        const float nm2 = fminf(fminf(m2, om2), fmaxf(m1, om1));
        if (om1 < m1 || (om1 == m1 && oi < i1)) { m1 = om1; i1 = oi; }
        m2 = nm2;
    }
    out[row] = i1;
    if (m2 - m1 <= EPS_GAP) {
        const int l = atomicAdd(&lcnt, 1);
        lrows[l] = row;
    }
    __syncthreads();

    const int n = lcnt;
    if (n > 0) {
        if (tid == 0) gbase = atomicAdd(ucount, (unsigned)n);
        __syncthreads();
        for (int i = 0; i < n; ++i) {
            const unsigned slot = gbase + i;
            if (slot >= (unsigned)CAP) break;
            const int r = lrows[i];
            if (tid == 0) urows[slot] = r;
#pragma unroll
            for (int e = 0; e < 4; ++e) {
                const int idx = e * 256 + tid;
                const float v = x[(size_t)r * D_DIM + idx];
                const _Float16 h = (_Float16)v;
                xch[(size_t)slot * D_DIM + idx] = h;
                xcl[(size_t)slot * D_DIM + idx] = (_Float16)(v - (float)h);
            }
        }
    }
}

// ============================================================================
// Rescore (K-split x8): exact 3-pass hi/lo over 512-col slice for 32 rows.
// ============================================================================
constexpr int R_XH = 0;        // 1024 halves (2 sub)
constexpr int R_XL = 1024;     // 1024
constexpr int R_CH = 2048;     // 8192 (16 sub)
constexpr int R_CL = 10240;    // 8192
constexpr int R_HB = 18432;    // per buffer (36 KB)

__global__ __launch_bounds__(256) void kmeans_rescore2(
    const _Float16* __restrict__ xch, const _Float16* __restrict__ xcl,
    const _Float16* __restrict__ ChiT, const _Float16* __restrict__ CloT,
    const float* __restrict__ Cnorm, const unsigned int* __restrict__ ucount,
    float* __restrict__ rpd, int* __restrict__ rpi)
{
    const unsigned cntr = *ucount;
    const unsigned cnt = cntr > (unsigned)CAP ? (unsigned)CAP : cntr;
    const int bid = blockIdx.x;
    const int ksl = bid & 7;
    const int grp = bid >> 3;
    if ((unsigned)(grp * 32) >= cnt) return;

    __shared__ _Float16 lds[2][R_HB];
    __shared__ float rd[32][4];
    __shared__ int   ri[32][4];

    const int tid  = threadIdx.x;
    const int lane = tid & 63;
    const int wid  = tid >> 6;
    const int l15  = lane & 15;
    const int l4   = lane >> 4;
    const int kge  = l4 ^ ((l15 >> 1) & 3);
    const int fragoff = l15 * 32 + kge * 8;
    const int scol = lane >> 2;
    const int skg  = (lane & 3) ^ ((scol >> 1) & 3);

    const int base  = grp * 32;
    const int kbase = ksl * (K_CENT / RSL);

    float best[2][4];
    int   bidx[2][4];
#pragma unroll
    for (int i = 0; i < 2; ++i)
#pragma unroll
        for (int r = 0; r < 4; ++r) { best[i][r] = 3.4e38f; bidx[i][r] = 0; }

    for (int ch = 0; ch < 2; ++ch) {
        const int kc = kbase + ch * 256;
        floatx4 acc[2][4];
#pragma unroll
        for (int i = 0; i < 2; ++i)
#pragma unroll
            for (int j = 0; j < 4; ++j) acc[i][j] = (floatx4)0.0f;

        {
            _Float16* buf = lds[0];
#pragma unroll
            for (int q = 0; q < 4; ++q) {
                const int sub = wid * 4 + q;
                gload_lds16(&ChiT[(size_t)(kc + sub * 16 + scol) * D_DIM + 0 + skg * 8], buf + R_CH + sub * 512);
                gload_lds16(&CloT[(size_t)(kc + sub * 16 + scol) * D_DIM + 0 + skg * 8], buf + R_CL + sub * 512);
            }
            if (wid < 2)
                gload_lds16(&xch[(size_t)(base + wid * 16 + scol) * D_DIM + 0 + skg * 8], buf + R_XH + wid * 512);
            else
                gload_lds16(&xcl[(size_t)(base + (wid - 2) * 16 + scol) * D_DIM + 0 + skg * 8], buf + R_XL + (wid - 2) * 512);
            __syncthreads();
        }

        for (int kdi = 0; kdi < D_DIM / 32; ++kdi) {
            const int cur = kdi & 1;
            _Float16* bufc = lds[cur];
            _Float16* bufn = lds[cur ^ 1];
            const int  kdn = (kdi + 1) * 32;
            const bool pf  = (kdi + 1 < D_DIM / 32);

            if (pf) {
#pragma unroll
                for (int q = 0; q < 4; ++q) {
                    const int sub = wid * 4 + q;
                    gload_lds16(&ChiT[(size_t)(kc + sub * 16 + scol) * D_DIM + kdn + skg * 8], bufn + R_CH + sub * 512);
                    gload_lds16(&CloT[(size_t)(kc + sub * 16 + scol) * D_DIM + kdn + skg * 8], bufn + R_CL + sub * 512);
                }
                if (wid < 2)
                    gload_lds16(&xch[(size_t)(base + wid * 16 + scol) * D_DIM + kdn + skg * 8], bufn + R_XH + wid * 512);
                else
                    gload_lds16(&xcl[(size_t)(base + (wid - 2) * 16 + scol) * D_DIM + kdn + skg * 8], bufn + R_XL + (wid - 2) * 512);
            }

            half8 ah[2], al[2], bh[4], bl[4];
#pragma unroll
            for (int i = 0; i < 2; ++i) {
                ah[i] = *(const half8*)(bufc + R_XH + i * 512 + fragoff);
                al[i] = *(const half8*)(bufc + R_XL + i * 512 + fragoff);
            }
#pragma unroll
            for (int j = 0; j < 4; ++j) {
                bh[j] = *(const half8*)(bufc + R_CH + (wid * 4 + j) * 512 + fragoff);
                bl[j] = *(const half8*)(bufc + R_CL + (wid * 4 + j) * 512 + fragoff);
            }
#pragma unroll
            for (int i = 0; i < 2; ++i)
#pragma unroll
                for (int j = 0; j < 4; ++j) {
                    acc[i][j] = __builtin_amdgcn_mfma_f32_16x16x32_f16(ah[i], bh[j], acc[i][j], 0, 0, 0);
                    acc[i][j] = __builtin_amdgcn_mfma_f32_16x16x32_f16(ah[i], bl[j], acc[i][j], 0, 0, 0);
                    acc[i][j] = __builtin_amdgcn_mfma_f32_16x16x32_f16(al[i], bh[j], acc[i][j], 0, 0, 0);
                }
            __syncthreads();
        }

#pragma unroll
        for (int j = 0; j < 4; ++j) {
            const int col = kc + wid * 64 + j * 16 + l15;
            const float cn = Cnorm[col];
#pragma unroll
            for (int i = 0; i < 2; ++i)
#pragma unroll
                for (int r = 0; r < 4; ++r) {
                    const float d = fmaf(-2.0f, acc[i][j][r], cn);
                    if (d < best[i][r]) { best[i][r] = d; bidx[i][r] = col; }
                }
        }
    }

#pragma unroll
    for (int i = 0; i < 2; ++i)
#pragma unroll
        for (int r = 0; r < 4; ++r) {
            float m1 = best[i][r];
            int   i1 = bidx[i][r];
#pragma unroll
            for (int off = 1; off < 16; off <<= 1) {
                const float om1 = __shfl_xor(m1, off, 64);
                const int   oi  = __shfl_xor(i1, off, 64);
                if (om1 < m1 || (om1 == m1 && oi < i1)) { m1 = om1; i1 = oi; }
            }
            if (l15 == 0) { rd[i * 16 + l4 * 4 + r][wid] = m1; ri[i * 16 + l4 * 4 + r][wid] = i1; }
        }
    __syncthreads();

    if (tid < 32) {
        float m1 = rd[tid][0];
        int   i1 = ri[tid][0];
#pragma unroll
        for (int w = 1; w < 4; ++w) {
            const float om1 = rd[tid][w];
            const int   oi  = ri[tid][w];
            if (om1 < m1 || (om1 == m1 && oi < i1)) { m1 = om1; i1 = oi; }
        }
        rpd[(size_t)(base + tid) * RSL + ksl] = m1;
        rpi[(size_t)(base + tid) * RSL + ksl] = i1;
    }
}

// ============================================================================
// Merge rescore slices -> final out for uncertain rows
// ============================================================================
__global__ __launch_bounds__(256) void kmeans_merge2(
    const float* __restrict__ rpd, const int* __restrict__ rpi,
    const int* __restrict__ urows, const unsigned int* __restrict__ ucount,
    int* __restrict__ out)
{
    const unsigned cntr = *ucount;
    const unsigned cnt = cntr > (unsigned)CAP ? (unsigned)CAP : cntr;
    const unsigned s = blockIdx.x * 256 + threadIdx.x;
    if (s >= cnt) return;
    float m1 = rpd[(size_t)s * RSL];
    int   i1 = rpi[(size_t)s * RSL];
#pragma unroll
    for (int k = 1; k < RSL; ++k) {
        const float om = rpd[(size_t)s * RSL + k];
        const int   oi = rpi[(size_t)s * RSL + k];
        if (om < m1 || (om == m1 && oi < i1)) { m1 = om; i1 = oi; }
    }
    out[urows[s]] = i1;
}

// ============================================================================
// Fallback A: proven R3 3-pass MFMA kernel (hi/lo, direct out)
// ============================================================================
constexpr int F_XH = 0, F_XL = 4096, F_CH = 8192, F_CL = 16384, F_HB = 24576;

__global__ __launch_bounds__(256) void convert_C_kernel(
    const float* __restrict__ C, _Float16* __restrict__ ChiT, _Float16* __restrict__ CloT)
{
    __shared__ float tile[32][33];
    const int bk = blockIdx.x, bd = blockIdx.y, t = threadIdx.x;
    const int r = t >> 3, c4 = (t & 7) * 4;
    const float4 v = *(const float4*)&C[(size_t)(bd * 32 + r) * K_CENT + bk * 32 + c4];
    tile[r][c4 + 0] = v.x; tile[r][c4 + 1] = v.y;
    tile[r][c4 + 2] = v.z; tile[r][c4 + 3] = v.w;
    __syncthreads();
    half4 h, l;
#pragma unroll
    for (int i = 0; i < 4; ++i) {
        const float f = tile[c4 + i][r];
        const _Float16 hi = (_Float16)f;
        h[i] = hi;
        l[i] = (_Float16)(f - (float)hi);
    }
    *(half4*)&ChiT[(size_t)(bk * 32 + r) * D_DIM + bd * 32 + c4] = h;
    *(half4*)&CloT[(size_t)(bk * 32 + r) * D_DIM + bd * 32 + c4] = l;
}

__device__ __forceinline__ void write_x2(_Float16* buf, const float4 v, int r, int kb) {
    const _Float16 h0 = (_Float16)v.x, h1 = (_Float16)v.y;
    const _Float16 h2 = (_Float16)v.z, h3 = (_Float16)v.w;
    const int kg  = kb >> 3;
    const int hs  = (kb >> 2) & 1;
    const int kge = kg ^ ((r >> 1) & 3);
    const int base = (r >> 4) * 512 + (r & 15) * 32 + kge * 8 + hs * 4;
    *(half4*)(buf + F_XH + base) = (half4){h0, h1, h2, h3};
    *(half4*)(buf + F_XL + base) = (half4){(_Float16)(v.x - (float)h0), (_Float16)(v.y - (float)h1),
                                           (_Float16)(v.z - (float)h2), (_Float16)(v.w - (float)h3)};
}

__global__ __launch_bounds__(512, 2) void kmeans_mfma_kernel(
    const float* __restrict__ x, const _Float16* __restrict__ ChiT,
    const _Float16* __restrict__ CloT, const float* __restrict__ Cnorm,
    int* __restrict__ out)
{
    __shared__ _Float16 lds[2][F_HB];
    __shared__ float red_d[2][64][4];
    __shared__ int   red_i[2][64][4];

    const int tid  = threadIdx.x;
    const int lane = tid & 63;
    const int wid  = tid >> 6;
    const int wm   = wid >> 2;
    const int wn   = wid & 3;
    const int row0 = blockIdx.x * 128;
    const int l15 = lane & 15;
    const int l4  = lane >> 4;
    const int kge = l4 ^ ((l15 >> 1) & 3);
    const int fragoff = l15 * 32 + kge * 8;
    const int sr = tid >> 2, sc = tid & 3;
    const int ccol = lane >> 2;
    const int ckg  = (lane & 3) ^ ((ccol >> 1) & 3);

    float best[4][4];
    int   bidx[4][4];
#pragma unroll
    for (int i = 0; i < 4; ++i)
#pragma unroll
        for (int r = 0; r < 4; ++r) { best[i][r] = 3.4e38f; bidx[i][r] = 0; }

    for (int kc = 0; kc < K_CENT; kc += 256) {
        floatx4 acc[4][4];
#pragma unroll
        for (int i = 0; i < 4; ++i)
#pragma unroll
            for (int j = 0; j < 4; ++j) acc[i][j] = (floatx4)0.0f;
        {
            _Float16* buf = lds[0];
            const float4 xv0 = *(const float4*)&x[(size_t)(row0 + sr) * D_DIM + 0 + sc * 4];
            const float4 xv1 = *(const float4*)&x[(size_t)(row0 + sr) * D_DIM + 16 + sc * 4];
            gload_lds16(&ChiT[(size_t)(kc + wid * 16 + ccol) * D_DIM + 0 + ckg * 8], buf + F_CH + wid * 512);
            gload_lds16(&ChiT[(size_t)(kc + (wid + 8) * 16 + ccol) * D_DIM + 0 + ckg * 8], buf + F_CH + (wid + 8) * 512);
            gload_lds16(&CloT[(size_t)(kc + wid * 16 + ccol) * D_DIM + 0 + ckg * 8], buf + F_CL + wid * 512);
            gload_lds16(&CloT[(size_t)(kc + (wid + 8) * 16 + ccol) * D_DIM + 0 + ckg * 8], buf + F_CL + (wid + 8) * 512);
            write_x2(buf, xv0, sr, sc * 4);
            write_x2(buf, xv1, sr, sc * 4 + 16);
            __syncthreads();
        }
        for (int kdi = 0; kdi < D_DIM / 32; ++kdi) {
            const int cur = kdi & 1;
            _Float16* bufc = lds[cur];
            _Float16* bufn = lds[cur ^ 1];
            const int  kdn = (kdi + 1) * 32;
            const bool pf  = (kdi + 1 < D_DIM / 32);
            float4 xv0, xv1;
            if (pf) {
                xv0 = *(const float4*)&x[(size_t)(row0 + sr) * D_DIM + kdn + sc * 4];
                xv1 = *(const float4*)&x[(size_t)(row0 + sr) * D_DIM + kdn + 16 + sc * 4];
                gload_lds16(&ChiT[(size_t)(kc + wid * 16 + ccol) * D_DIM + kdn + ckg * 8], bufn + F_CH + wid * 512);
                gload_lds16(&ChiT[(size_t)(kc + (wid + 8) * 16 + ccol) * D_DIM + kdn + ckg * 8], bufn + F_CH + (wid + 8) * 512);
                gload_lds16(&CloT[(size_t)(kc + wid * 16 + ccol) * D_DIM + kdn + ckg * 8], bufn + F_CL + wid * 512);
                gload_lds16(&CloT[(size_t)(kc + (wid + 8) * 16 + ccol) * D_DIM + kdn + ckg * 8], bufn + F_CL + (wid + 8) * 512);
            }
            half8 ah[4], al[4], bh[4], bl[4];
#pragma unroll
            for (int i = 0; i < 4; ++i) {
                ah[i] = *(const half8*)(bufc + F_XH + (wm * 4 + i) * 512 + fragoff);
                al[i] = *(const half8*)(bufc + F_XL + (wm * 4 + i) * 512 + fragoff);
            }
#pragma unroll
            for (int j = 0; j < 4; ++j) {
                bh[j] = *(const half8*)(bufc + F_CH + (wn * 4 + j) * 512 + fragoff);
                bl[j] = *(const half8*)(bufc + F_CL + (wn * 4 + j) * 512 + fragoff);
            }
#pragma unroll
            for (int i = 0; i < 4; ++i)
#pragma unroll
                for (int j = 0; j < 4; ++j) {
                    acc[i][j] = __builtin_amdgcn_mfma_f32_16x16x32_f16(ah[i], bh[j], acc[i][j], 0, 0, 0);
                    acc[i][j] = __builtin_amdgcn_mfma_f32_16x16x32_f16(ah[i], bl[j], acc[i][j], 0, 0, 0);
                    acc[i][j] = __builtin_amdgcn_mfma_f32_16x16x32_f16(al[i], bh[j], acc[i][j], 0, 0, 0);
                }
            if (pf) {
                write_x2(bufn, xv0, sr, sc * 4);
                write_x2(bufn, xv1, sr, sc * 4 + 16);
            }
            __syncthreads();
        }
        const int colw = kc + wn * 64;
#pragma unroll
        for (int ns = 0; ns < 4; ++ns) {
            const float cn = Cnorm[colw + ns * 16 + l15];
            const int   ix = colw + ns * 16 + l15;
#pragma unroll
            for (int i = 0; i < 4; ++i)
#pragma unroll
                for (int r = 0; r < 4; ++r) {
                    const float d = fmaf(-2.0f, acc[i][ns][r], cn);
                    if (d < best[i][r]) { best[i][r] = d; bidx[i][r] = ix; }
                }
        }
    }
#pragma unroll
    for (int i = 0; i < 4; ++i)
#pragma unroll
        for (int r = 0; r < 4; ++r) {
            float d  = best[i][r];
            int   ix = bidx[i][r];
#pragma unroll
            for (int off = 1; off < 16; off <<= 1) {
                const float od = __shfl_xor(d, off, 64);
                const int   oi = __shfl_xor(ix, off, 64);
                if (od < d || (od == d && oi < ix)) { d = od; ix = oi; }
            }
            if (l15 == 0) {
                red_d[wm][i * 16 + l4 * 4 + r][wn] = d;
                red_i[wm][i * 16 + l4 * 4 + r][wn] = ix;
            }
        }
    __syncthreads();
    if (tid < 128) {
        const int hh = tid >> 6, rr = tid & 63;
        float bd = red_d[hh][rr][0];
        int   bi2 = red_i[hh][rr][0];
#pragma unroll
        for (int w = 1; w < 4; ++w) {
            const float od = red_d[hh][rr][w];
            const int   oi = red_i[hh][rr][w];
            if (od < bd || (od == bd && oi < bi2)) { bd = od; bi2 = oi; }
        }
        out[row0 + tid] = bi2;
    }
}

// ============================================================================
// Fallback B: R1 fp32 kernel
// ============================================================================
__global__ __launch_bounds__(256, 2) void kmeans_assign_f32(
    const float* __restrict__ x, const float* __restrict__ Cm,
    const float* __restrict__ Cnorm, int* __restrict__ out)
{
    __shared__ float xs[32][64];
    __shared__ float cs[32][64];
    const int tid = threadIdx.x;
    const int tx = tid & 15, ty = tid >> 4;
    const int row0 = blockIdx.x * 64;
    const int xr = tid >> 3, xc = tid & 7;
    const int cr = tid >> 4, cc = tid & 15;
    float best[4]; int bidx[4];
#pragma unroll
    for (int i = 0; i < 4; ++i) { best[i] = 3.4e38f; bidx[i] = 0; }
    for (int kc = 0; kc < K_CENT; kc += 64) {
        float acc[16];
#pragma unroll
        for (int i = 0; i < 16; ++i) acc[i] = 0.0f;
        for (int kd = 0; kd < D_DIM; kd += 32) {
            const float4 xv0 = *(const float4*)&x[(size_t)(row0 + xr) * D_DIM + kd + xc * 4];
            const float4 xv1 = *(const float4*)&x[(size_t)(row0 + xr + 32) * D_DIM + kd + xc * 4];
            const float4 cv0 = *(const float4*)&Cm[(size_t)(kd + cr) * K_CENT + kc + cc * 4];
            const float4 cv1 = *(const float4*)&Cm[(size_t)(kd + cr + 16) * K_CENT + kc + cc * 4];
            __syncthreads();
            xs[xc*4+0][xr] = xv0.x; xs[xc*4+1][xr] = xv0.y; xs[xc*4+2][xr] = xv0.z; xs[xc*4+3][xr] = xv0.w;
            xs[xc*4+0][xr+32] = xv1.x; xs[xc*4+1][xr+32] = xv1.y; xs[xc*4+2][xr+32] = xv1.z; xs[xc*4+3][xr+32] = xv1.w;
            *(float4*)&cs[cr][cc*4]    = cv0;
            *(float4*)&cs[cr+16][cc*4] = cv1;
            __syncthreads();
#pragma unroll
            for (int kk = 0; kk < 32; ++kk) {
                const float4 a = *(const float4*)&xs[kk][ty*4];
                const float4 b = *(const float4*)&cs[kk][tx*4];
                acc[ 0] += a.x*b.x; acc[ 1] += a.x*b.y; acc[ 2] += a.x*b.z; acc[ 3] += a.x*b.w;
                acc[ 4] += a.y*b.x; acc[ 5] += a.y*b.y; acc[ 6] += a.y*b.z; acc[ 7] += a.y*b.w;
                acc[ 8] += a.z*b.x; acc[ 9] += a.z*b.y; acc[10] += a.z*b.z; acc[11] += a.z*b.w;
                acc[12] += a.w*b.x; acc[13] += a.w*b.y; acc[14] += a.w*b.z; acc[15] += a.w*b.w;
            }
        }
        const float4 cn = *(const float4*)&Cnorm[kc + tx*4];
        const float cnv[4] = {cn.x, cn.y, cn.z, cn.w};
#pragma unroll
        for (int i = 0; i < 4; ++i)
#pragma unroll
            for (int j = 0; j < 4; ++j) {
                const float dist = cnv[j] - 2.0f * acc[i*4+j];
                const int   idx  = kc + tx*4 + j;
                if (dist < best[i]) { best[i] = dist; bidx[i] = idx; }
            }
    }
#pragma unroll
    for (int i = 0; i < 4; ++i) {
        float d = best[i]; int ix = bidx[i];
#pragma unroll
        for (int off = 1; off < 16; off <<= 1) {
            const float od = __shfl_xor(d, off, 64);
            const int   oi = __shfl_xor(ix, off, 64);
            if (od < d || (od == d && oi < ix)) { d = od; ix = oi; }
        }
        if (tx == 0) out[row0 + ty*4 + i] = ix;
    }
}

// ============================================================================
extern "C" void kernel_launch(void* const* d_in, const int* in_sizes, int n_in,
                              void* d_out, int out_size, void* d_ws, size_t ws_size,
                              hipStream_t stream) {
    const float* x     = (const float*)d_in[0];
    const float* C     = (const float*)d_in[1];
    const float* Cnorm = (const float*)d_in[2];
    int* out = (int*)d_out;

    const size_t chalf = (size_t)K_CENT * D_DIM;   // halves per C array
    const size_t capd  = (size_t)CAP * D_DIM;      // halves per xc array
    const size_t xhN   = (size_t)N_ROWS * D_DIM;   // halves for x_hi

    const size_t sz_base = (2 * chalf + 2 * capd) * 2
                         + (size_t)KSL * N_ROWS * 12
                         + (size_t)CAP * RSL * 8
                         + (size_t)CAP * 4 + 64;
    const size_t need_full = sz_base + xhN * 2;
    const size_t need_r3   = 2 * chalf * 2;

    if (ws_size >= need_full) {
        _Float16* ChiT = (_Float16*)d_ws;
        _Float16* CloT = ChiT + chalf;
        _Float16* xch  = CloT + chalf;
        _Float16* xcl  = xch + capd;
        float* m1buf = (float*)(xcl + capd);
        float* m2buf = m1buf + (size_t)KSL * N_ROWS;
        int*   i1buf = (int*)(m2buf + (size_t)KSL * N_ROWS);
        float* rpd   = (float*)(i1buf + (size_t)KSL * N_ROWS);
        int*   rpi   = (int*)(rpd + (size_t)CAP * RSL);
        int*   urows = rpi + (size_t)CAP * RSL;
        unsigned int* ucount = (unsigned int*)(urows + CAP);
        _Float16* xh = (_Float16*)(ucount + 16);

        convert_all<<<dim3(4096 + (int)(xhN / 2048)), 256, 0, stream>>>(C, x, ChiT, CloT, xh, ucount);
        kmeans_pass1<<<dim3(256 * KSL), 256, 0, stream>>>(xh, ChiT, Cnorm, m1buf, i1buf, m2buf);
        kmeans_merge_gather<<<dim3(N_ROWS / 256), 256, 0, stream>>>(m1buf, i1buf, m2buf, x, out, urows, ucount, xch, xcl);
        kmeans_rescore2<<<dim3((CAP / 32) * RSL), 256, 0, stream>>>(xch, xcl, ChiT, CloT, Cnorm, ucount, rpd, rpi);
        kmeans_merge2<<<dim3(CAP / 256), 256, 0, stream>>>(rpd, rpi, urows, ucount, out);
    } else if (ws_size >= need_r3) {
        _Float16* ChiT = (_Float16*)d_ws;
        _Float16* CloT = ChiT + chalf;
        convert_C_kernel<<<dim3(128, 32), 256, 0, stream>>>(C, ChiT, CloT);
        kmeans_mfma_kernel<<<dim3(N_ROWS / 128), 512, 0, stream>>>(x, ChiT, CloT, Cnorm, out);
    } else {
        kmeans_assign_f32<<<dim3(N_ROWS / 64), 256, 0, stream>>>(x, C, Cnorm, out);
    }
}